// Round 3
// baseline (252.588 us; speedup 1.0000x reference)
//
#include <hip/hip_runtime.h>
#include <cstdint>

#define BATCH 8
#define T_SEQ 2048
#define E_DIM 1024
#define H_DIM 64
#define BT (BATCH * T_SEQ)

// ---------------- QKV projection: q/k/v = x @ Wq/Wk/Wv ----------------
// x:[BT,E] fp32, W:[E,64] fp32 -> [BT,64] fp32 each.
#define PBM 64
#define PBK 32
#define XSTR 68   // padded leading dim for transposed x tile (conflict-free b128)

__global__ __launch_bounds__(256, 1) void qkv_proj_kernel(
    const float* __restrict__ x,
    const float* __restrict__ Wk,
    const float* __restrict__ Wq,
    const float* __restrict__ Wv,
    float* __restrict__ qws,
    float* __restrict__ kws,
    float* __restrict__ vws)
{
    __shared__ __align__(16) float xs[PBK][XSTR];
    __shared__ __align__(16) float wk_s[PBK][H_DIM];
    __shared__ __align__(16) float wq_s[PBK][H_DIM];
    __shared__ __align__(16) float wv_s[PBK][H_DIM];

    const int tid  = threadIdx.x;
    const int row0 = blockIdx.x * PBM;
    const int tx   = tid & 15;   // output col group (4 cols)
    const int ty   = tid >> 4;   // output row group (4 rows)

    const int lr = tid >> 2;          // 0..63: x row for staging
    const int lk = (tid & 3) * 8;     // 8-float k-chunk

    float aK[4][4] = {{0.f,0.f,0.f,0.f},{0.f,0.f,0.f,0.f},{0.f,0.f,0.f,0.f},{0.f,0.f,0.f,0.f}};
    float aQ[4][4] = {{0.f,0.f,0.f,0.f},{0.f,0.f,0.f,0.f},{0.f,0.f,0.f,0.f},{0.f,0.f,0.f,0.f}};
    float aV[4][4] = {{0.f,0.f,0.f,0.f},{0.f,0.f,0.f,0.f},{0.f,0.f,0.f,0.f},{0.f,0.f,0.f,0.f}};

    for (int k0 = 0; k0 < E_DIM; k0 += PBK) {
        __syncthreads();
        // ---- stage x tile, transposed: xs[kk][row] ----
        {
            const float* xp = x + (size_t)(row0 + lr) * E_DIM + (k0 + lk);
            const float4 xa = *reinterpret_cast<const float4*>(xp);
            const float4 xb = *reinterpret_cast<const float4*>(xp + 4);
            xs[lk + 0][lr] = xa.x; xs[lk + 1][lr] = xa.y;
            xs[lk + 2][lr] = xa.z; xs[lk + 3][lr] = xa.w;
            xs[lk + 4][lr] = xb.x; xs[lk + 5][lr] = xb.y;
            xs[lk + 6][lr] = xb.z; xs[lk + 7][lr] = xb.w;
        }
        // ---- stage W tiles (each 32x64 fp32; 512 float4 / 256 thr = 2 per thread) ----
        {
            const int i0 = tid, i1 = tid + 256;
            const int ka = i0 >> 4, ca = (i0 & 15) << 2;
            const int kb = i1 >> 4, cb = (i1 & 15) << 2;
            const size_t ga = (size_t)(k0 + ka) * H_DIM + ca;
            const size_t gb = (size_t)(k0 + kb) * H_DIM + cb;
            *reinterpret_cast<float4*>(&wk_s[ka][ca]) = *reinterpret_cast<const float4*>(Wk + ga);
            *reinterpret_cast<float4*>(&wk_s[kb][cb]) = *reinterpret_cast<const float4*>(Wk + gb);
            *reinterpret_cast<float4*>(&wq_s[ka][ca]) = *reinterpret_cast<const float4*>(Wq + ga);
            *reinterpret_cast<float4*>(&wq_s[kb][cb]) = *reinterpret_cast<const float4*>(Wq + gb);
            *reinterpret_cast<float4*>(&wv_s[ka][ca]) = *reinterpret_cast<const float4*>(Wv + ga);
            *reinterpret_cast<float4*>(&wv_s[kb][cb]) = *reinterpret_cast<const float4*>(Wv + gb);
        }
        __syncthreads();

        #pragma unroll
        for (int kk = 0; kk < PBK; ++kk) {
            const float4 a  = *reinterpret_cast<const float4*>(&xs[kk][ty << 2]);
            const float4 bk = *reinterpret_cast<const float4*>(&wk_s[kk][tx << 2]);
            const float4 bq = *reinterpret_cast<const float4*>(&wq_s[kk][tx << 2]);
            const float4 bv = *reinterpret_cast<const float4*>(&wv_s[kk][tx << 2]);
            const float av[4]  = {a.x,  a.y,  a.z,  a.w};
            const float bkv[4] = {bk.x, bk.y, bk.z, bk.w};
            const float bqv[4] = {bq.x, bq.y, bq.z, bq.w};
            const float bvv[4] = {bv.x, bv.y, bv.z, bv.w};
            #pragma unroll
            for (int i = 0; i < 4; ++i) {
                #pragma unroll
                for (int j = 0; j < 4; ++j) {
                    aK[i][j] = fmaf(av[i], bkv[j], aK[i][j]);
                    aQ[i][j] = fmaf(av[i], bqv[j], aQ[i][j]);
                    aV[i][j] = fmaf(av[i], bvv[j], aV[i][j]);
                }
            }
        }
    }

    #pragma unroll
    for (int i = 0; i < 4; ++i) {
        const size_t off = (size_t)(row0 + (ty << 2) + i) * H_DIM + (tx << 2);
        *reinterpret_cast<float4*>(qws + off) = make_float4(aQ[i][0], aQ[i][1], aQ[i][2], aQ[i][3]);
        *reinterpret_cast<float4*>(kws + off) = make_float4(aK[i][0], aK[i][1], aK[i][2], aK[i][3]);
        *reinterpret_cast<float4*>(vws + off) = make_float4(aV[i][0], aV[i][1], aV[i][2], aV[i][3]);
    }
}

// ---------------- Flash attention (causal, online softmax), fp32 ----------------
#define QB 32
#define KB 64
#define KSTR 68
#define PSTR 68

__global__ __launch_bounds__(512, 1) void attn_kernel(
    const float* __restrict__ q,
    const float* __restrict__ k,
    const float* __restrict__ v,
    float* __restrict__ out)
{
    __shared__ __align__(16) float Ks[KB][KSTR];
    __shared__ __align__(16) float Vs[KB][KSTR];
    __shared__ __align__(16) float Ps[QB][PSTR];

    const int tid  = threadIdx.x;
    const int bb   = blockIdx.x >> 5;     // batch
    const int pair = blockIdx.x & 31;     // folded q-tile pair index
    const int r    = tid >> 4;            // 0..31 row within q-tile
    const int cg   = tid & 15;            // 16-lane column/h group

    const int nQ = T_SEQ / QB;            // 64

    for (int half = 0; half < 2; ++half) {
        const int p  = half ? (nQ - 1 - pair) : pair;   // balanced causal work
        const int q0 = p * QB;
        const int qg = q0 + r;

        // Q row in registers, pre-scaled by 1/sqrt(64)
        float4 qreg[16];
        const float* qrow = q + ((size_t)bb * T_SEQ + qg) * H_DIM;
        #pragma unroll
        for (int d4 = 0; d4 < 16; ++d4) {
            const float4 t = *reinterpret_cast<const float4*>(qrow + (d4 << 2));
            qreg[d4] = make_float4(t.x * 0.125f, t.y * 0.125f, t.z * 0.125f, t.w * 0.125f);
        }

        float o0 = 0.f, o1 = 0.f, o2 = 0.f, o3 = 0.f;
        float m = -1e30f, l = 0.f;

        const int kt = (q0 + QB - 1) / KB + 1;
        for (int kb = 0; kb < kt; ++kb) {
            __syncthreads();
            // ---- stage K,V tiles (64x64 each; 1024 float4 / 512 thr = 2 each) ----
            {
                const float* kp = k + ((size_t)bb * T_SEQ + (size_t)kb * KB) * H_DIM;
                const float* vp = v + ((size_t)bb * T_SEQ + (size_t)kb * KB) * H_DIM;
                #pragma unroll
                for (int i = 0; i < 2; ++i) {
                    const int idx = tid + (i << 9);           // 0..1023
                    const int rr = idx >> 4, c4 = (idx & 15) << 2;
                    *reinterpret_cast<float4*>(&Ks[rr][c4]) =
                        *reinterpret_cast<const float4*>(kp + (size_t)rr * H_DIM + c4);
                    *reinterpret_cast<float4*>(&Vs[rr][c4]) =
                        *reinterpret_cast<const float4*>(vp + (size_t)rr * H_DIM + c4);
                }
            }
            __syncthreads();

            // ---- S = (Q/8) . K^T for 4 strided columns c = cg + 16j ----
            float s[4] = {0.f, 0.f, 0.f, 0.f};
            #pragma unroll
            for (int d4 = 0; d4 < 16; ++d4) {
                const float4 qv = qreg[d4];
                #pragma unroll
                for (int j = 0; j < 4; ++j) {
                    const float4 kv = *reinterpret_cast<const float4*>(&Ks[cg + (j << 4)][d4 << 2]);
                    s[j] += qv.x * kv.x + qv.y * kv.y + qv.z * kv.z + qv.w * kv.w;
                }
            }
            // ---- causal mask (only the last tile can cross the diagonal) ----
            if (kb == kt - 1) {
                #pragma unroll
                for (int j = 0; j < 4; ++j) {
                    const int kg = kb * KB + cg + (j << 4);
                    if (kg > qg) s[j] = -1e30f;
                }
            }
            // ---- online softmax (row spread over 16 lanes) ----
            float tmax = fmaxf(fmaxf(s[0], s[1]), fmaxf(s[2], s[3]));
            tmax = fmaxf(tmax, __shfl_xor(tmax, 1));
            tmax = fmaxf(tmax, __shfl_xor(tmax, 2));
            tmax = fmaxf(tmax, __shfl_xor(tmax, 4));
            tmax = fmaxf(tmax, __shfl_xor(tmax, 8));
            const float mnew  = fmaxf(m, tmax);
            const float scale = __expf(m - mnew);
            m = mnew;
            float ps = 0.f;
            #pragma unroll
            for (int j = 0; j < 4; ++j) { s[j] = __expf(s[j] - mnew); ps += s[j]; }
            ps += __shfl_xor(ps, 1); ps += __shfl_xor(ps, 2);
            ps += __shfl_xor(ps, 4); ps += __shfl_xor(ps, 8);
            l = l * scale + ps;
            o0 *= scale; o1 *= scale; o2 *= scale; o3 *= scale;
            #pragma unroll
            for (int j = 0; j < 4; ++j) Ps[r][cg + (j << 4)] = s[j];
            __syncthreads();

            // ---- O += P @ V (thread owns 4 h at h0 = cg*4) ----
            #pragma unroll
            for (int c = 0; c < KB; ++c) {
                const float pv = Ps[r][c];
                const float4 vv = *reinterpret_cast<const float4*>(&Vs[c][cg << 2]);
                o0 = fmaf(pv, vv.x, o0);
                o1 = fmaf(pv, vv.y, o1);
                o2 = fmaf(pv, vv.z, o2);
                o3 = fmaf(pv, vv.w, o3);
            }
        }
        // ---- write normalized output ----
        const float inv = 1.f / l;
        float* orow = out + ((size_t)bb * T_SEQ + qg) * H_DIM + (cg << 2);
        *reinterpret_cast<float4*>(orow) = make_float4(o0 * inv, o1 * inv, o2 * inv, o3 * inv);
    }
}

extern "C" void kernel_launch(void* const* d_in, const int* in_sizes, int n_in,
                              void* d_out, int out_size, void* d_ws, size_t ws_size,
                              hipStream_t stream) {
    const float* x  = (const float*)d_in[0];
    const float* Wk = (const float*)d_in[1];
    const float* Wq = (const float*)d_in[2];
    const float* Wv = (const float*)d_in[3];
    float* out = (float*)d_out;

    float* ws  = (float*)d_ws;
    const size_t N = (size_t)BT * H_DIM;
    float* qws = ws;
    float* kws = ws + N;
    float* vws = ws + 2 * N;

    qkv_proj_kernel<<<BT / PBM, 256, 0, stream>>>(x, Wk, Wq, Wv, qws, kws, vws);
    attn_kernel<<<BATCH * (T_SEQ / QB / 2), 512, 0, stream>>>(qws, kws, vws, out);
}

// Round 4
// 109.126 us; speedup vs baseline: 2.3146x; 2.3146x over previous
//
#include <hip/hip_runtime.h>
#include <cstdint>

#define BATCH 8
#define T_SEQ 2048
#define E_DIM 1024
#define H_DIM 64
#define BT (BATCH * T_SEQ)

typedef __attribute__((ext_vector_type(8))) short bf16x8;   // 8 bf16 = 4 VGPR
typedef __attribute__((ext_vector_type(4))) float f32x4;

// fp32 -> bf16 bits, round-to-nearest-even
static __device__ __forceinline__ short f2bf(float f) {
    uint32_t b = __float_as_uint(f);
    b += 0x7fffu + ((b >> 16) & 1u);
    return (short)(b >> 16);
}

// ws element offsets (short units)
#define Q_OFF   0
#define K_OFF   (BT * H_DIM)            // 1048576
#define VT_OFF  (2 * BT * H_DIM)
#define WT_OFF  (3 * BT * H_DIM)        // Wt bf16 [3][64][1024]

// ---------- kernel 1: W -> Wt (transposed, bf16): Wt[m][col][k] ----------
__global__ void wt_prep(const float* __restrict__ Wk, const float* __restrict__ Wq,
                        const float* __restrict__ Wv, short* __restrict__ wt) {
    int idx = blockIdx.x * 256 + threadIdx.x;      // 0 .. 3*65536-1
    int m = idx >> 16;
    int r = idx & 65535;
    int c = r >> 10;            // col 0..63
    int k = r & 1023;           // k 0..1023
    const float* W = (m == 0) ? Wk : ((m == 1) ? Wq : Wv);
    wt[(((m << 6) + c) << 10) + k] = f2bf(W[(k << 6) + c]);
}

// ---------- kernel 2: qkv projection via MFMA ----------
// x fp32 [BT][1024]; Wt bf16 [3][64][1024]  (m: 0=K,1=Q,2=V)
// outputs: q bf16 [BT][64] (pre-scaled by 0.125), k bf16 [BT][64], vT bf16 [B][64][T]
__global__ __launch_bounds__(256, 1) void proj_mfma(
    const float* __restrict__ x, const short* __restrict__ wt,
    short* __restrict__ qo, short* __restrict__ ko, short* __restrict__ vto)
{
    // A-tile in MFMA-fragment order: chunk = band*2+s (8), slot = lane, 8 bf16 each
    __shared__ __align__(16) short xs[8 * 64 * 8];   // 8 KB

    const int tid  = threadIdx.x;
    const int lane = tid & 63;
    const int w    = tid >> 6;          // wave = row band 0..3
    const int row0 = blockIdx.x * 64;

    const f32x4 z4 = {0.f, 0.f, 0.f, 0.f};
    f32x4 acc[3][4];
    #pragma unroll
    for (int m = 0; m < 3; ++m)
        #pragma unroll
        for (int ct = 0; ct < 4; ++ct) acc[m][ct] = z4;

    for (int k0 = 0; k0 < E_DIM; k0 += 64) {
        __syncthreads();
        // stage x tile (64 rows x 64 k) as bf16 fragments
        #pragma unroll
        for (int g = 0; g < 2; ++g) {
            int lin = tid * 2 + g;                 // 0..511
            int row = lin >> 3, k8 = lin & 7;
            const float* xp = x + (size_t)(row0 + row) * E_DIM + k0 + k8 * 8;
            float4 a = *reinterpret_cast<const float4*>(xp);
            float4 b = *reinterpret_cast<const float4*>(xp + 4);
            bf16x8 v;
            v[0] = f2bf(a.x); v[1] = f2bf(a.y); v[2] = f2bf(a.z); v[3] = f2bf(a.w);
            v[4] = f2bf(b.x); v[5] = f2bf(b.y); v[6] = f2bf(b.z); v[7] = f2bf(b.w);
            int chunk = ((row >> 4) << 1) | (k8 >> 2);
            int slot  = ((k8 & 3) << 4) | (row & 15);
            *reinterpret_cast<bf16x8*>(&xs[(chunk * 64 + slot) * 8]) = v;
        }
        __syncthreads();

        #pragma unroll
        for (int s = 0; s < 2; ++s) {
            bf16x8 afrag = *reinterpret_cast<const bf16x8*>(&xs[((w * 2 + s) * 64 + lane) * 8]);
            int kg = k0 + s * 32 + ((lane >> 4) << 3);
            #pragma unroll
            for (int m = 0; m < 3; ++m) {
                #pragma unroll
                for (int ct = 0; ct < 4; ++ct) {
                    const short* bp = wt + ((size_t)((m << 6) + (ct << 4) + (lane & 15)) << 10) + kg;
                    bf16x8 bfrag = *reinterpret_cast<const bf16x8*>(bp);
                    acc[m][ct] = __builtin_amdgcn_mfma_f32_16x16x32_bf16(afrag, bfrag, acc[m][ct], 0, 0, 0);
                }
            }
        }
    }

    // epilogue: D layout col=lane&15, row=(lane>>4)*4+i  [verified]
    const int rbase = row0 + (w << 4) + ((lane >> 4) << 2);
    #pragma unroll
    for (int ct = 0; ct < 4; ++ct) {
        int col = (ct << 4) + (lane & 15);
        #pragma unroll
        for (int i = 0; i < 4; ++i) {
            int row = rbase + i;
            ko[(size_t)row * H_DIM + col] = f2bf(acc[0][ct][i]);
            qo[(size_t)row * H_DIM + col] = f2bf(acc[1][ct][i] * 0.125f);  // fold softmax scale (exact)
            // vT[b][col][tok]
            vto[((size_t)((row >> 11) << 6) + col) * T_SEQ + (row & 2047)] = f2bf(acc[2][ct][i]);
        }
    }
}

// ---------- kernel 3: causal flash attention via MFMA ----------
// q,k bf16 [BT][64] (q pre-scaled); vt bf16 [B][64][T]; out fp32 [BT][64]
#define SWZ(row, off) ((off) ^ (((row) & 7) << 3))   // element-index swizzle (16B granules)

__global__ __launch_bounds__(256, 1) void attn_mfma(
    const short* __restrict__ q, const short* __restrict__ k,
    const short* __restrict__ vt, float* __restrict__ out)
{
    __shared__ __align__(16) short Kt[2][64 * 64];   // [parity buf][kr][d]  swizzled
    __shared__ __align__(16) short Vt[2][64 * 64];   // [parity buf][d][kt]  swizzled
    __shared__ __align__(16) short Ps[4][16 * 64];   // per-wave P tile      swizzled
    __shared__ float Om[2][16][64];
    __shared__ float Mm[2][16];
    __shared__ float Lm[2][16];

    const int tid  = threadIdx.x;
    const int lane = tid & 63;
    const int w    = tid >> 6;
    const int band = w & 1;       // q sub-band (16 rows)
    const int par  = w >> 1;      // K-tile parity
    const int bb   = blockIdx.x >> 5;
    const int pairi = blockIdx.x & 31;

    for (int half = 0; half < 2; ++half) {
        const int p  = half ? (63 - pairi) : pairi;   // q-tile 0..63 (QB=32), balanced fold
        const int q0 = p << 5;
        const int Nt = (p >> 1) + 1;                  // K-tiles of 64
        const int npair = (Nt + 1) >> 1;

        // Q A-fragments (rows = lane&15, k-chunks of 8)
        const int qrowA = q0 + (band << 4) + (lane & 15);
        bf16x8 qf[2];
        #pragma unroll
        for (int s = 0; s < 2; ++s)
            qf[s] = *reinterpret_cast<const bf16x8*>(
                q + (size_t)(bb * T_SEQ + qrowA) * H_DIM + s * 32 + ((lane >> 4) << 3));

        const f32x4 z4 = {0.f, 0.f, 0.f, 0.f};
        float mreg[4] = {-1e30f, -1e30f, -1e30f, -1e30f};
        float lreg[4] = {0.f, 0.f, 0.f, 0.f};
        f32x4 oacc[4] = {z4, z4, z4, z4};

        for (int it = 0; it < npair; ++it) {
            __syncthreads();
            // stage K-tiles 2it (buf0) and 2it+1 (buf1): K rows + vT rows, swizzled b128 writes
            #pragma unroll
            for (int tt = 0; tt < 2; ++tt) {
                int t = (it << 1) + tt;
                if (t < Nt) {
                    #pragma unroll
                    for (int part = 0; part < 2; ++part) {
                        int lin = part * 256 + tid;          // 0..511
                        int row = lin >> 3, c8 = lin & 7;
                        int off = row * 64 + SWZ(row, c8 * 8);
                        bf16x8 kv = *reinterpret_cast<const bf16x8*>(
                            k + (size_t)(bb * T_SEQ + t * 64 + row) * H_DIM + c8 * 8);
                        *reinterpret_cast<bf16x8*>(&Kt[tt][off]) = kv;
                        bf16x8 vv = *reinterpret_cast<const bf16x8*>(
                            vt + ((size_t)(bb << 6) + row) * T_SEQ + t * 64 + c8 * 8);
                        *reinterpret_cast<bf16x8*>(&Vt[tt][off]) = vv;
                    }
                }
            }
            __syncthreads();

            int tm = (it << 1) + par;
            if (tm < Nt) {
                // ---- S = Q . K^T  (16q x 64kc) ----
                f32x4 sacc[4] = {z4, z4, z4, z4};
                #pragma unroll
                for (int s = 0; s < 2; ++s) {
                    int doff = s * 32 + ((lane >> 4) << 3);
                    #pragma unroll
                    for (int ct = 0; ct < 4; ++ct) {
                        int kr = (ct << 4) + (lane & 15);
                        bf16x8 bf = *reinterpret_cast<const bf16x8*>(&Kt[par][kr * 64 + SWZ(kr, doff)]);
                        sacc[ct] = __builtin_amdgcn_mfma_f32_16x16x32_bf16(qf[s], bf, sacc[ct], 0, 0, 0);
                    }
                }
                // ---- causal mask (only last tile crosses diagonal) ----
                if (tm == Nt - 1) {
                    int qgb = q0 + (band << 4) + ((lane >> 4) << 2);
                    #pragma unroll
                    for (int ct = 0; ct < 4; ++ct) {
                        int kg = tm * 64 + (ct << 4) + (lane & 15);
                        #pragma unroll
                        for (int i = 0; i < 4; ++i)
                            if (kg > qgb + i) sacc[ct][i] = -1e30f;
                    }
                }
                // ---- online softmax (rows = (lane>>4)*4+i, cols across 16 lanes) ----
                #pragma unroll
                for (int i = 0; i < 4; ++i) {
                    float s0 = sacc[0][i], s1 = sacc[1][i], s2 = sacc[2][i], s3 = sacc[3][i];
                    float tmax = fmaxf(fmaxf(s0, s1), fmaxf(s2, s3));
                    tmax = fmaxf(tmax, __shfl_xor(tmax, 1));
                    tmax = fmaxf(tmax, __shfl_xor(tmax, 2));
                    tmax = fmaxf(tmax, __shfl_xor(tmax, 4));
                    tmax = fmaxf(tmax, __shfl_xor(tmax, 8));
                    float mnew = fmaxf(mreg[i], tmax);
                    float sc = __expf(mreg[i] - mnew);
                    mreg[i] = mnew;
                    float p0 = __expf(s0 - mnew), p1 = __expf(s1 - mnew);
                    float p2 = __expf(s2 - mnew), p3 = __expf(s3 - mnew);
                    float ps = p0 + p1 + p2 + p3;
                    ps += __shfl_xor(ps, 1); ps += __shfl_xor(ps, 2);
                    ps += __shfl_xor(ps, 4); ps += __shfl_xor(ps, 8);
                    lreg[i] = lreg[i] * sc + ps;
                    oacc[0][i] *= sc; oacc[1][i] *= sc; oacc[2][i] *= sc; oacc[3][i] *= sc;
                    int rq = ((lane >> 4) << 2) + i;
                    short* pr = &Ps[w][rq * 64];
                    pr[SWZ(rq, (0 << 4) + (lane & 15))] = f2bf(p0);
                    pr[SWZ(rq, (1 << 4) + (lane & 15))] = f2bf(p1);
                    pr[SWZ(rq, (2 << 4) + (lane & 15))] = f2bf(p2);
                    pr[SWZ(rq, (3 << 4) + (lane & 15))] = f2bf(p3);
                }
                // ---- O += P . V ----
                int qa = lane & 15;
                #pragma unroll
                for (int dt = 0; dt < 4; ++dt) {
                    int vr = (dt << 4) + (lane & 15);
                    #pragma unroll
                    for (int s = 0; s < 2; ++s) {
                        int koff = s * 32 + ((lane >> 4) << 3);
                        bf16x8 af = *reinterpret_cast<const bf16x8*>(&Ps[w][qa * 64 + SWZ(qa, koff)]);
                        bf16x8 bf = *reinterpret_cast<const bf16x8*>(&Vt[par][vr * 64 + SWZ(vr, koff)]);
                        oacc[dt] = __builtin_amdgcn_mfma_f32_16x16x32_bf16(af, bf, oacc[dt], 0, 0, 0);
                    }
                }
            }
        }

        // ---- merge the two parity states per band, write output ----
        __syncthreads();
        if (par == 1) {
            int rq0 = (lane >> 4) << 2;
            #pragma unroll
            for (int dt = 0; dt < 4; ++dt)
                #pragma unroll
                for (int i = 0; i < 4; ++i)
                    Om[band][rq0 + i][(dt << 4) + (lane & 15)] = oacc[dt][i];
            if ((lane & 15) == 0) {
                #pragma unroll
                for (int i = 0; i < 4; ++i) { Mm[band][rq0 + i] = mreg[i]; Lm[band][rq0 + i] = lreg[i]; }
            }
        }
        __syncthreads();
        if (par == 0) {
            #pragma unroll
            for (int i = 0; i < 4; ++i) {
                int rq = ((lane >> 4) << 2) + i;
                float m1 = Mm[band][rq], l1 = Lm[band][rq];
                float mm = fmaxf(mreg[i], m1);
                float f0 = __expf(mreg[i] - mm), f1 = __expf(m1 - mm);
                float inv = 1.f / (lreg[i] * f0 + l1 * f1);
                size_t orow = (size_t)(bb * T_SEQ + q0 + (band << 4) + rq) * H_DIM;
                #pragma unroll
                for (int dt = 0; dt < 4; ++dt) {
                    float o1 = Om[band][rq][(dt << 4) + (lane & 15)];
                    out[orow + (dt << 4) + (lane & 15)] = (oacc[dt][i] * f0 + o1 * f1) * inv;
                }
            }
        }
        __syncthreads();
    }
}

extern "C" void kernel_launch(void* const* d_in, const int* in_sizes, int n_in,
                              void* d_out, int out_size, void* d_ws, size_t ws_size,
                              hipStream_t stream) {
    const float* x  = (const float*)d_in[0];
    const float* Wk = (const float*)d_in[1];
    const float* Wq = (const float*)d_in[2];
    const float* Wv = (const float*)d_in[3];
    float* out = (float*)d_out;

    short* ws  = (short*)d_ws;
    short* qb  = ws + Q_OFF;
    short* kb  = ws + K_OFF;
    short* vtb = ws + VT_OFF;
    short* wtb = ws + WT_OFF;

    wt_prep<<<768, 256, 0, stream>>>(Wk, Wq, Wv, wtb);
    proj_mfma<<<BT / 64, 256, 0, stream>>>(x, wtb, qb, kb, vtb);
    attn_mfma<<<BATCH * 32, 256, 0, stream>>>(qb, kb, vtb, out);
}

// Round 5
// 86.250 us; speedup vs baseline: 2.9286x; 1.2652x over previous
//
#include <hip/hip_runtime.h>
#include <cstdint>

#define BATCH 8
#define T_SEQ 2048
#define E_DIM 1024
#define H_DIM 64
#define BT (BATCH * T_SEQ)

typedef __attribute__((ext_vector_type(8))) short bf16x8;   // 8 bf16 = 4 VGPR
typedef __attribute__((ext_vector_type(4))) float f32x4;
typedef __attribute__((ext_vector_type(4))) short s16x4;

// fp32 -> bf16 bits, round-to-nearest-even
static __device__ __forceinline__ short f2bf(float f) {
    uint32_t b = __float_as_uint(f);
    b += 0x7fffu + ((b >> 16) & 1u);
    return (short)(b >> 16);
}

// ws element offsets (short units)
#define Q_OFF   0
#define K_OFF   (BT * H_DIM)
#define VT_OFF  (2 * BT * H_DIM)
#define WT_OFF  (3 * BT * H_DIM)        // Wt bf16 [3][64][1024]

// ---------- kernel 1: W -> Wt (transposed, bf16): Wt[m][col][k] ----------
__global__ void wt_prep(const float* __restrict__ Wk, const float* __restrict__ Wq,
                        const float* __restrict__ Wv, short* __restrict__ wt) {
    int idx = blockIdx.x * 256 + threadIdx.x;      // 0 .. 3*65536-1
    int m = idx >> 16;
    int r = idx & 65535;
    int c = r >> 10;            // col 0..63
    int k = r & 1023;           // k 0..1023
    const float* W = (m == 0) ? Wk : ((m == 1) ? Wq : Wv);
    wt[(((m << 6) + c) << 10) + k] = f2bf(W[(k << 6) + c]);
}

// ---------- kernel 2: qkv projection, split-K across waves, no main-loop barriers ----------
// x fp32 [BT][1024]; Wt bf16 [3][64][1024] (m: 0=K,1=Q,2=V)
// out: k bf16 [BT][64], q bf16 [BT][64] (pre-scaled 0.125), vT bf16 [B][64][T]
#define MST 196   // fp32 merge-buffer stride: 16B-aligned rows, 4-row offset != 0 mod 32 banks

__device__ __forceinline__ void dump_acc(const f32x4 (&acc)[3][4][2], float (*buf)[MST], int lane) {
    const int l15 = lane & 15, r4 = (lane >> 4) << 2;
    #pragma unroll
    for (int m = 0; m < 3; ++m)
        #pragma unroll
        for (int ct = 0; ct < 4; ++ct)
            #pragma unroll
            for (int rb = 0; rb < 2; ++rb)
                #pragma unroll
                for (int i = 0; i < 4; ++i)
                    buf[(rb << 4) + r4 + i][(m << 6) + (ct << 4) + l15] = acc[m][ct][rb][i];
}

__device__ __forceinline__ void add_acc(f32x4 (&acc)[3][4][2], const float (*buf)[MST], int lane) {
    const int l15 = lane & 15, r4 = (lane >> 4) << 2;
    #pragma unroll
    for (int m = 0; m < 3; ++m)
        #pragma unroll
        for (int ct = 0; ct < 4; ++ct)
            #pragma unroll
            for (int rb = 0; rb < 2; ++rb)
                #pragma unroll
                for (int i = 0; i < 4; ++i)
                    acc[m][ct][rb][i] += buf[(rb << 4) + r4 + i][(m << 6) + (ct << 4) + l15];
}

__global__ __launch_bounds__(256, 2) void proj_mfma(
    const float* __restrict__ x, const short* __restrict__ wt,
    short* __restrict__ qo, short* __restrict__ ko, short* __restrict__ vto)
{
    __shared__ float mA[32][MST];   // 24.5 KB
    __shared__ float mB[32][MST];

    const int tid  = threadIdx.x;
    const int lane = tid & 63;
    const int w    = tid >> 6;          // wave = k-slab 0..3 (256 k each)
    const int row0 = blockIdx.x * 32;
    const int l15  = lane & 15;
    const int lk8  = (lane >> 4) << 3;

    const f32x4 z4 = {0.f, 0.f, 0.f, 0.f};
    f32x4 acc[3][4][2];
    #pragma unroll
    for (int m = 0; m < 3; ++m)
        #pragma unroll
        for (int ct = 0; ct < 4; ++ct) { acc[m][ct][0] = z4; acc[m][ct][1] = z4; }

    const float* xb0 = x + (size_t)(row0 + l15) * E_DIM + (w << 8) + lk8;
    const float* xb1 = xb0 + 16 * E_DIM;
    const short* wb  = wt + ((size_t)l15 << 10) + (w << 8) + lk8;

    #pragma unroll 2
    for (int ks = 0; ks < 256; ks += 32) {
        float4 a0 = *reinterpret_cast<const float4*>(xb0 + ks);
        float4 a1 = *reinterpret_cast<const float4*>(xb0 + ks + 4);
        float4 b0 = *reinterpret_cast<const float4*>(xb1 + ks);
        float4 b1 = *reinterpret_cast<const float4*>(xb1 + ks + 4);
        bf16x8 af0, af1;
        af0[0] = f2bf(a0.x); af0[1] = f2bf(a0.y); af0[2] = f2bf(a0.z); af0[3] = f2bf(a0.w);
        af0[4] = f2bf(a1.x); af0[5] = f2bf(a1.y); af0[6] = f2bf(a1.z); af0[7] = f2bf(a1.w);
        af1[0] = f2bf(b0.x); af1[1] = f2bf(b0.y); af1[2] = f2bf(b0.z); af1[3] = f2bf(b0.w);
        af1[4] = f2bf(b1.x); af1[5] = f2bf(b1.y); af1[6] = f2bf(b1.z); af1[7] = f2bf(b1.w);
        #pragma unroll
        for (int m = 0; m < 3; ++m)
            #pragma unroll
            for (int ct = 0; ct < 4; ++ct) {
                bf16x8 bf = *reinterpret_cast<const bf16x8*>(wb + ((size_t)((m << 2) + ct) << 14) + ks);
                acc[m][ct][0] = __builtin_amdgcn_mfma_f32_16x16x32_bf16(af0, bf, acc[m][ct][0], 0, 0, 0);
                acc[m][ct][1] = __builtin_amdgcn_mfma_f32_16x16x32_bf16(af1, bf, acc[m][ct][1], 0, 0, 0);
            }
    }

    // ---- merge 4 k-partials: tree through LDS ----
    if (w == 2) dump_acc(acc, mA, lane);
    if (w == 3) dump_acc(acc, mB, lane);
    __syncthreads();
    if (w == 0) add_acc(acc, mA, lane);
    if (w == 1) { add_acc(acc, mB, lane); dump_acc(acc, mB, lane); }
    __syncthreads();
    if (w == 0) { add_acc(acc, mB, lane); dump_acc(acc, mA, lane); }
    __syncthreads();

    // ---- cooperative cvt+store: 32 rows x 192 cols fp32 in mA ----
    const int row  = tid >> 3;            // 0..31
    const int grow = row0 + row;
    const int bidx = grow >> 11, tok = grow & 2047;
    #pragma unroll
    for (int j = 0; j < 6; ++j) {
        const int c   = (tid & 7) * 6 + j;      // 0..47 (vec4 index; col = 4c)
        const int m   = c >> 4;
        const f32x4 val = *reinterpret_cast<const f32x4*>(&mA[row][c << 2]);
        if (m == 2) {          // V -> vT[b][col][tok]
            #pragma unroll
            for (int e = 0; e < 4; ++e)
                vto[((size_t)(bidx << 6) + ((c & 15) << 2) + e) * T_SEQ + tok] = f2bf(val[e]);
        } else {
            s16x4 o;
            const float sc = (m == 1) ? 0.125f : 1.0f;
            #pragma unroll
            for (int e = 0; e < 4; ++e) o[e] = f2bf(val[e] * sc);
            short* dst = ((m == 0) ? ko : qo) + (size_t)grow * H_DIM + (((c & 15)) << 2);
            *reinterpret_cast<s16x4*>(dst) = o;
        }
    }
}

// ---------- kernel 3: causal flash attention via MFMA ----------
// q,k bf16 [BT][64] (q pre-scaled); vt bf16 [B][64][T]; out fp32 [BT][64]
#define SWZ(row, off) ((off) ^ (((row) & 7) << 3))   // element-index swizzle (16B granules)

__global__ __launch_bounds__(256, 2) void attn_mfma(
    const short* __restrict__ q, const short* __restrict__ k,
    const short* __restrict__ vt, float* __restrict__ out)
{
    __shared__ __align__(16) short Kt[2][64 * 64];   // [parity buf][kr][d]  swizzled
    __shared__ __align__(16) short Vt[2][64 * 64];   // [parity buf][d][kt]  swizzled
    __shared__ __align__(16) short Ps[4][16 * 64];   // per-wave P tile      swizzled
    __shared__ float Om[2][16][64];
    __shared__ float Mm[2][16];
    __shared__ float Lm[2][16];

    const int tid  = threadIdx.x;
    const int lane = tid & 63;
    const int w    = tid >> 6;
    const int band = w & 1;       // q sub-band (16 rows)
    const int par  = w >> 1;      // K-tile parity
    const int bb   = blockIdx.x & 7;
    const int p    = 63 - (blockIdx.x >> 3);   // heavy q-tiles dispatched first (LPT)

    const int q0 = p << 5;
    const int Nt = (p >> 1) + 1;                  // K-tiles of 64
    const int npair = (Nt + 1) >> 1;

    // Q A-fragments (rows = lane&15, k-chunks of 8)
    const int qrowA = q0 + (band << 4) + (lane & 15);
    bf16x8 qf[2];
    #pragma unroll
    for (int s = 0; s < 2; ++s)
        qf[s] = *reinterpret_cast<const bf16x8*>(
            q + (size_t)(bb * T_SEQ + qrowA) * H_DIM + s * 32 + ((lane >> 4) << 3));

    const f32x4 z4 = {0.f, 0.f, 0.f, 0.f};
    float mreg[4] = {-1e30f, -1e30f, -1e30f, -1e30f};
    float lreg[4] = {0.f, 0.f, 0.f, 0.f};
    f32x4 oacc[4] = {z4, z4, z4, z4};

    for (int it = 0; it < npair; ++it) {
        __syncthreads();
        // stage K-tiles 2it (buf0) and 2it+1 (buf1): K rows + vT rows, swizzled b128 writes
        #pragma unroll
        for (int tt = 0; tt < 2; ++tt) {
            int t = (it << 1) + tt;
            if (t < Nt) {
                #pragma unroll
                for (int part = 0; part < 2; ++part) {
                    int lin = part * 256 + tid;          // 0..511
                    int row = lin >> 3, c8 = lin & 7;
                    int off = row * 64 + SWZ(row, c8 * 8);
                    bf16x8 kv = *reinterpret_cast<const bf16x8*>(
                        k + (size_t)(bb * T_SEQ + t * 64 + row) * H_DIM + c8 * 8);
                    *reinterpret_cast<bf16x8*>(&Kt[tt][off]) = kv;
                    bf16x8 vv = *reinterpret_cast<const bf16x8*>(
                        vt + ((size_t)(bb << 6) + row) * T_SEQ + t * 64 + c8 * 8);
                    *reinterpret_cast<bf16x8*>(&Vt[tt][off]) = vv;
                }
            }
        }
        __syncthreads();

        int tm = (it << 1) + par;
        if (tm < Nt) {
            // ---- S = Q . K^T  (16q x 64kc) ----
            f32x4 sacc[4] = {z4, z4, z4, z4};
            #pragma unroll
            for (int s = 0; s < 2; ++s) {
                int doff = s * 32 + ((lane >> 4) << 3);
                #pragma unroll
                for (int ct = 0; ct < 4; ++ct) {
                    int kr = (ct << 4) + (lane & 15);
                    bf16x8 bf = *reinterpret_cast<const bf16x8*>(&Kt[par][kr * 64 + SWZ(kr, doff)]);
                    sacc[ct] = __builtin_amdgcn_mfma_f32_16x16x32_bf16(qf[s], bf, sacc[ct], 0, 0, 0);
                }
            }
            // ---- causal mask (only last tile crosses diagonal) ----
            if (tm == Nt - 1) {
                int qgb = q0 + (band << 4) + ((lane >> 4) << 2);
                #pragma unroll
                for (int ct = 0; ct < 4; ++ct) {
                    int kg = tm * 64 + (ct << 4) + (lane & 15);
                    #pragma unroll
                    for (int i = 0; i < 4; ++i)
                        if (kg > qgb + i) sacc[ct][i] = -1e30f;
                }
            }
            // ---- online softmax (rows = (lane>>4)*4+i, cols across 16 lanes) ----
            #pragma unroll
            for (int i = 0; i < 4; ++i) {
                float s0 = sacc[0][i], s1 = sacc[1][i], s2 = sacc[2][i], s3 = sacc[3][i];
                float tmax = fmaxf(fmaxf(s0, s1), fmaxf(s2, s3));
                tmax = fmaxf(tmax, __shfl_xor(tmax, 1));
                tmax = fmaxf(tmax, __shfl_xor(tmax, 2));
                tmax = fmaxf(tmax, __shfl_xor(tmax, 4));
                tmax = fmaxf(tmax, __shfl_xor(tmax, 8));
                float mnew = fmaxf(mreg[i], tmax);
                float sc = __expf(mreg[i] - mnew);
                mreg[i] = mnew;
                float p0 = __expf(s0 - mnew), p1 = __expf(s1 - mnew);
                float p2 = __expf(s2 - mnew), p3 = __expf(s3 - mnew);
                float ps = p0 + p1 + p2 + p3;
                ps += __shfl_xor(ps, 1); ps += __shfl_xor(ps, 2);
                ps += __shfl_xor(ps, 4); ps += __shfl_xor(ps, 8);
                lreg[i] = lreg[i] * sc + ps;
                oacc[0][i] *= sc; oacc[1][i] *= sc; oacc[2][i] *= sc; oacc[3][i] *= sc;
                int rq = ((lane >> 4) << 2) + i;
                short* pr = &Ps[w][rq * 64];
                pr[SWZ(rq, (0 << 4) + (lane & 15))] = f2bf(p0);
                pr[SWZ(rq, (1 << 4) + (lane & 15))] = f2bf(p1);
                pr[SWZ(rq, (2 << 4) + (lane & 15))] = f2bf(p2);
                pr[SWZ(rq, (3 << 4) + (lane & 15))] = f2bf(p3);
            }
            // ---- O += P . V ----
            int qa = lane & 15;
            #pragma unroll
            for (int dt = 0; dt < 4; ++dt) {
                int vr = (dt << 4) + (lane & 15);
                #pragma unroll
                for (int s = 0; s < 2; ++s) {
                    int koff = s * 32 + ((lane >> 4) << 3);
                    bf16x8 af = *reinterpret_cast<const bf16x8*>(&Ps[w][qa * 64 + SWZ(qa, koff)]);
                    bf16x8 bf = *reinterpret_cast<const bf16x8*>(&Vt[par][vr * 64 + SWZ(vr, koff)]);
                    oacc[dt] = __builtin_amdgcn_mfma_f32_16x16x32_bf16(af, bf, oacc[dt], 0, 0, 0);
                }
            }
        }
    }

    // ---- merge the two parity states per band, write output ----
    __syncthreads();
    if (par == 1) {
        int rq0 = (lane >> 4) << 2;
        #pragma unroll
        for (int dt = 0; dt < 4; ++dt)
            #pragma unroll
            for (int i = 0; i < 4; ++i)
                Om[band][rq0 + i][(dt << 4) + (lane & 15)] = oacc[dt][i];
        if ((lane & 15) == 0) {
            #pragma unroll
            for (int i = 0; i < 4; ++i) { Mm[band][rq0 + i] = mreg[i]; Lm[band][rq0 + i] = lreg[i]; }
        }
    }
    __syncthreads();
    if (par == 0) {
        #pragma unroll
        for (int i = 0; i < 4; ++i) {
            int rq = ((lane >> 4) << 2) + i;
            float m1 = Mm[band][rq], l1 = Lm[band][rq];
            float mm = fmaxf(mreg[i], m1);
            float f0 = __expf(mreg[i] - mm), f1 = __expf(m1 - mm);
            float inv = 1.f / (lreg[i] * f0 + l1 * f1);
            size_t orow = (size_t)(bb * T_SEQ + q0 + (band << 4) + rq) * H_DIM;
            #pragma unroll
            for (int dt = 0; dt < 4; ++dt) {
                float o1 = Om[band][rq][(dt << 4) + (lane & 15)];
                out[orow + (dt << 4) + (lane & 15)] = (oacc[dt][i] * f0 + o1 * f1) * inv;
            }
        }
    }
}

extern "C" void kernel_launch(void* const* d_in, const int* in_sizes, int n_in,
                              void* d_out, int out_size, void* d_ws, size_t ws_size,
                              hipStream_t stream) {
    const float* x  = (const float*)d_in[0];
    const float* Wk = (const float*)d_in[1];
    const float* Wq = (const float*)d_in[2];
    const float* Wv = (const float*)d_in[3];
    float* out = (float*)d_out;

    short* ws  = (short*)d_ws;
    short* qb  = ws + Q_OFF;
    short* kb  = ws + K_OFF;
    short* vtb = ws + VT_OFF;
    short* wtb = ws + WT_OFF;

    wt_prep<<<768, 256, 0, stream>>>(Wk, Wq, Wv, wtb);
    proj_mfma<<<BT / 32, 256, 0, stream>>>(x, wtb, qb, kb, vtb);
    attn_mfma<<<512, 256, 0, stream>>>(qb, kb, vtb, out);
}

// Round 6
// 76.794 us; speedup vs baseline: 3.2892x; 1.1231x over previous
//
#include <hip/hip_runtime.h>
#include <cstdint>

#define BATCH 8
#define T_SEQ 2048
#define E_DIM 1024
#define H_DIM 64
#define BT (BATCH * T_SEQ)

typedef __attribute__((ext_vector_type(8))) short bf16x8;   // 8 bf16 = 4 VGPR
typedef __attribute__((ext_vector_type(4))) float f32x4;
typedef __attribute__((ext_vector_type(4))) short s16x4;

// fp32 -> bf16 bits, round-to-nearest-even
static __device__ __forceinline__ short f2bf(float f) {
    uint32_t b = __float_as_uint(f);
    b += 0x7fffu + ((b >> 16) & 1u);
    return (short)(b >> 16);
}

// ws element offsets (short units)
#define Q_OFF   0
#define K_OFF   (BT * H_DIM)
#define VT_OFF  (2 * BT * H_DIM)
#define WT_OFF  (3 * BT * H_DIM)            // 384 KB region (either wt layout)
#define XB_OFF  (WT_OFF + 3 * 64 * 1024)    // xb fragment-linear bf16 (33.5 MB)

static __device__ __forceinline__ void glds16(const void* g, void* l) {
    __builtin_amdgcn_global_load_lds(
        (const __attribute__((address_space(1))) void*)g,
        (__attribute__((address_space(3))) void*)l, 16, 0, 0);
}

// ================= FAST PATH =================
// Fragment-linear layouts (verified mapping from R4/R5 passing kernels):
//   A-frag lane l: row = l&15, k = (l>>4)*8 + e    (16 rows x 32 k per 1KB tile)
//   xb  [rt][kt][lane][8]  rt=row/16 (1024), kt=k/32 (32)
//   wt_b[f][kt][lane][8]   f = m*4+ct (12), col = ct*16 + (l&15)

// ---- W -> wt_b (fragment-linear bf16) ----
__global__ void wt_prep_frag(const float* __restrict__ Wk, const float* __restrict__ Wq,
                             const float* __restrict__ Wv, short* __restrict__ wtb) {
    int gid = blockIdx.x * 256 + threadIdx.x;       // 0..24575
    int lane = gid & 63;
    int kt = (gid >> 6) & 31;
    int f = gid >> 11;                               // 0..11
    int m = f >> 2, ct = f & 3;
    int col = (ct << 4) | (lane & 15);
    int k0 = (kt << 5) | (((lane >> 4) & 3) << 3);
    const float* W = (m == 0) ? Wk : ((m == 1) ? Wq : Wv);
    bf16x8 v;
    #pragma unroll
    for (int e = 0; e < 8; ++e) v[e] = f2bf(W[(size_t)(k0 + e) * H_DIM + col]);
    *reinterpret_cast<bf16x8*>(wtb + (size_t)gid * 8) = v;
}

// ---- x fp32 -> xb bf16 fragment-linear (streaming) ----
__global__ __launch_bounds__(256) void xcvt(const float* __restrict__ x, short* __restrict__ xb) {
    int gid = blockIdx.x * 256 + threadIdx.x;       // one bf16x8 per thread
    int lane = gid & 63;
    int kt = (gid >> 6) & 31;
    int rt = gid >> 11;
    int row = (rt << 4) | (lane & 15);
    int k0 = (kt << 5) | (((lane >> 4) & 3) << 3);
    const float* xp = x + (size_t)row * E_DIM + k0;
    float4 a = *reinterpret_cast<const float4*>(xp);
    float4 b = *reinterpret_cast<const float4*>(xp + 4);
    bf16x8 v;
    v[0] = f2bf(a.x); v[1] = f2bf(a.y); v[2] = f2bf(a.z); v[3] = f2bf(a.w);
    v[4] = f2bf(b.x); v[5] = f2bf(b.y); v[6] = f2bf(b.z); v[7] = f2bf(b.w);
    *reinterpret_cast<bf16x8*>(xb + (size_t)gid * 8) = v;
}

// ---- projection: A direct 1KB frag loads, B glds-staged, split-K x2 ----
__global__ __launch_bounds__(256, 2) void proj2(
    const short* __restrict__ xb, const short* __restrict__ wtb,
    short* __restrict__ qo, short* __restrict__ ko, short* __restrict__ vto)
{
    __shared__ __align__(16) short Bs[2][24 * 512];   // 2 x 24KB (24 chunks of 1KB)

    const int tid  = threadIdx.x;
    const int lane = tid & 63;
    const int w    = tid >> 6;
    const int kh   = w >> 1;             // k-half (512 k each)
    const int rtl  = w & 1;              // row-tile within block
    const int rt_g = blockIdx.x * 2 + rtl;           // 16-row tile id

    const f32x4 z4 = {0.f, 0.f, 0.f, 0.f};
    f32x4 acc[12];
    #pragma unroll
    for (int f = 0; f < 12; ++f) acc[f] = z4;

    const short* abase = xb + ((size_t)rt_g * 32 + kh * 16) * 512 + lane * 8;

    // stage step s (kt = khc*16+s for both halves) into Bs[buf]
    #define STAGE(buf, s)                                                              \
        {                                                                              \
            _Pragma("unroll")                                                          \
            for (int ci = 0; ci < 6; ++ci) {                                           \
                int c = w * 6 + ci;                                                    \
                int f = c % 12, khc = c / 12;                                          \
                const short* src = wtb + (((size_t)f * 32 + khc * 16 + (s)) * 64 + lane) * 8; \
                glds16(src, &Bs[buf][c * 512]);                                        \
            }                                                                          \
        }

    STAGE(0, 0);
    bf16x8 afc = *reinterpret_cast<const bf16x8*>(abase);
    __syncthreads();

    int buf = 0;
    bf16x8 afn;
    for (int s = 0; s < 16; ++s) {
        if (s < 15) {
            STAGE(buf ^ 1, s + 1);
            afn = *reinterpret_cast<const bf16x8*>(abase + (size_t)(s + 1) * 512);
        }
        #pragma unroll
        for (int f = 0; f < 12; ++f) {
            bf16x8 bfv = *reinterpret_cast<const bf16x8*>(&Bs[buf][(kh * 12 + f) * 512 + lane * 8]);
            acc[f] = __builtin_amdgcn_mfma_f32_16x16x32_bf16(afc, bfv, acc[f], 0, 0, 0);
        }
        __syncthreads();
        afc = afn;
        buf ^= 1;
    }

    // merge k-halves: kh1 dumps to LDS (aliases Bs[0], last reads were Bs[1])
    float* mrg = reinterpret_cast<float*>(&Bs[0][0]);
    if (kh == 1) {
        #pragma unroll
        for (int f = 0; f < 12; ++f)
            *reinterpret_cast<f32x4*>(mrg + ((size_t)(rtl * 12 + f) * 64 + lane) * 4) = acc[f];
    }
    __syncthreads();
    if (kh == 0) {
        const int col16 = lane & 15, rowb = (lane >> 4) << 2;
        const int R0 = rt_g * 16 + rowb;
        #pragma unroll
        for (int m = 0; m < 3; ++m) {
            #pragma unroll
            for (int ct = 0; ct < 4; ++ct) {
                int f = m * 4 + ct;
                f32x4 v = acc[f];
                f32x4 o = *reinterpret_cast<const f32x4*>(mrg + ((size_t)(rtl * 12 + f) * 64 + lane) * 4);
                v.x += o.x; v.y += o.y; v.z += o.z; v.w += o.w;
                int C = (ct << 4) | col16;
                #pragma unroll
                for (int i = 0; i < 4; ++i) {
                    int R = R0 + i;
                    if (m == 0)      ko[(size_t)R * H_DIM + C] = f2bf(v[i]);
                    else if (m == 1) qo[(size_t)R * H_DIM + C] = f2bf(v[i] * 0.125f);
                    else             vto[((size_t)(R >> 11) * 64 + C) * T_SEQ + (R & 2047)] = f2bf(v[i]);
                }
            }
        }
    }
}

// ================= FALLBACK PATH (R5, proven) =================
__global__ void wt_prep_old(const float* __restrict__ Wk, const float* __restrict__ Wq,
                            const float* __restrict__ Wv, short* __restrict__ wt) {
    int idx = blockIdx.x * 256 + threadIdx.x;
    int m = idx >> 16;
    int r = idx & 65535;
    int c = r >> 10;
    int k = r & 1023;
    const float* W = (m == 0) ? Wk : ((m == 1) ? Wq : Wv);
    wt[(((m << 6) + c) << 10) + k] = f2bf(W[(k << 6) + c]);
}

#define MST 196
__device__ __forceinline__ void dump_acc(const f32x4 (&acc)[3][4][2], float (*buf)[MST], int lane) {
    const int l15 = lane & 15, r4 = (lane >> 4) << 2;
    #pragma unroll
    for (int m = 0; m < 3; ++m)
        #pragma unroll
        for (int ct = 0; ct < 4; ++ct)
            #pragma unroll
            for (int rb = 0; rb < 2; ++rb)
                #pragma unroll
                for (int i = 0; i < 4; ++i)
                    buf[(rb << 4) + r4 + i][(m << 6) + (ct << 4) + l15] = acc[m][ct][rb][i];
}
__device__ __forceinline__ void add_acc(f32x4 (&acc)[3][4][2], const float (*buf)[MST], int lane) {
    const int l15 = lane & 15, r4 = (lane >> 4) << 2;
    #pragma unroll
    for (int m = 0; m < 3; ++m)
        #pragma unroll
        for (int ct = 0; ct < 4; ++ct)
            #pragma unroll
            for (int rb = 0; rb < 2; ++rb)
                #pragma unroll
                for (int i = 0; i < 4; ++i)
                    acc[m][ct][rb][i] += buf[(rb << 4) + r4 + i][(m << 6) + (ct << 4) + l15];
}

__global__ __launch_bounds__(256, 2) void proj_old(
    const float* __restrict__ x, const short* __restrict__ wt,
    short* __restrict__ qo, short* __restrict__ ko, short* __restrict__ vto)
{
    __shared__ float mA[32][MST];
    __shared__ float mB[32][MST];
    const int tid  = threadIdx.x;
    const int lane = tid & 63;
    const int w    = tid >> 6;
    const int row0 = blockIdx.x * 32;
    const int l15  = lane & 15;
    const int lk8  = (lane >> 4) << 3;
    const f32x4 z4 = {0.f, 0.f, 0.f, 0.f};
    f32x4 acc[3][4][2];
    #pragma unroll
    for (int m = 0; m < 3; ++m)
        #pragma unroll
        for (int ct = 0; ct < 4; ++ct) { acc[m][ct][0] = z4; acc[m][ct][1] = z4; }
    const float* xb0 = x + (size_t)(row0 + l15) * E_DIM + (w << 8) + lk8;
    const float* xb1 = xb0 + 16 * E_DIM;
    const short* wb  = wt + ((size_t)l15 << 10) + (w << 8) + lk8;
    #pragma unroll 2
    for (int ks = 0; ks < 256; ks += 32) {
        float4 a0 = *reinterpret_cast<const float4*>(xb0 + ks);
        float4 a1 = *reinterpret_cast<const float4*>(xb0 + ks + 4);
        float4 b0 = *reinterpret_cast<const float4*>(xb1 + ks);
        float4 b1 = *reinterpret_cast<const float4*>(xb1 + ks + 4);
        bf16x8 af0, af1;
        af0[0] = f2bf(a0.x); af0[1] = f2bf(a0.y); af0[2] = f2bf(a0.z); af0[3] = f2bf(a0.w);
        af0[4] = f2bf(a1.x); af0[5] = f2bf(a1.y); af0[6] = f2bf(a1.z); af0[7] = f2bf(a1.w);
        af1[0] = f2bf(b0.x); af1[1] = f2bf(b0.y); af1[2] = f2bf(b0.z); af1[3] = f2bf(b0.w);
        af1[4] = f2bf(b1.x); af1[5] = f2bf(b1.y); af1[6] = f2bf(b1.z); af1[7] = f2bf(b1.w);
        #pragma unroll
        for (int m = 0; m < 3; ++m)
            #pragma unroll
            for (int ct = 0; ct < 4; ++ct) {
                bf16x8 bfv = *reinterpret_cast<const bf16x8*>(wb + ((size_t)((m << 2) + ct) << 14) + ks);
                acc[m][ct][0] = __builtin_amdgcn_mfma_f32_16x16x32_bf16(af0, bfv, acc[m][ct][0], 0, 0, 0);
                acc[m][ct][1] = __builtin_amdgcn_mfma_f32_16x16x32_bf16(af1, bfv, acc[m][ct][1], 0, 0, 0);
            }
    }
    if (w == 2) dump_acc(acc, mA, lane);
    if (w == 3) dump_acc(acc, mB, lane);
    __syncthreads();
    if (w == 0) add_acc(acc, mA, lane);
    if (w == 1) { add_acc(acc, mB, lane); dump_acc(acc, mB, lane); }
    __syncthreads();
    if (w == 0) { add_acc(acc, mB, lane); dump_acc(acc, mA, lane); }
    __syncthreads();
    const int row  = tid >> 3;
    const int grow = row0 + row;
    const int bidx = grow >> 11, tok = grow & 2047;
    #pragma unroll
    for (int j = 0; j < 6; ++j) {
        const int c   = (tid & 7) * 6 + j;
        const int m   = c >> 4;
        const f32x4 val = *reinterpret_cast<const f32x4*>(&mA[row][c << 2]);
        if (m == 2) {
            #pragma unroll
            for (int e = 0; e < 4; ++e)
                vto[((size_t)(bidx << 6) + ((c & 15) << 2) + e) * T_SEQ + tok] = f2bf(val[e]);
        } else {
            s16x4 o;
            const float sc = (m == 1) ? 0.125f : 1.0f;
            #pragma unroll
            for (int e = 0; e < 4; ++e) o[e] = f2bf(val[e] * sc);
            short* dst = ((m == 0) ? ko : qo) + (size_t)grow * H_DIM + (((c & 15)) << 2);
            *reinterpret_cast<s16x4*>(dst) = o;
        }
    }
}

// ================= attention (R5, passing) =================
#define SWZ(row, off) ((off) ^ (((row) & 7) << 3))

__global__ __launch_bounds__(256, 2) void attn_mfma(
    const short* __restrict__ q, const short* __restrict__ k,
    const short* __restrict__ vt, float* __restrict__ out)
{
    __shared__ __align__(16) short Kt[2][64 * 64];
    __shared__ __align__(16) short Vt[2][64 * 64];
    __shared__ __align__(16) short Ps[4][16 * 64];
    __shared__ float Om[2][16][64];
    __shared__ float Mm[2][16];
    __shared__ float Lm[2][16];

    const int tid  = threadIdx.x;
    const int lane = tid & 63;
    const int w    = tid >> 6;
    const int band = w & 1;
    const int par  = w >> 1;
    const int bb   = blockIdx.x & 7;
    const int p    = 63 - (blockIdx.x >> 3);

    const int q0 = p << 5;
    const int Nt = (p >> 1) + 1;
    const int npair = (Nt + 1) >> 1;

    const int qrowA = q0 + (band << 4) + (lane & 15);
    bf16x8 qf[2];
    #pragma unroll
    for (int s = 0; s < 2; ++s)
        qf[s] = *reinterpret_cast<const bf16x8*>(
            q + (size_t)(bb * T_SEQ + qrowA) * H_DIM + s * 32 + ((lane >> 4) << 3));

    const f32x4 z4 = {0.f, 0.f, 0.f, 0.f};
    float mreg[4] = {-1e30f, -1e30f, -1e30f, -1e30f};
    float lreg[4] = {0.f, 0.f, 0.f, 0.f};
    f32x4 oacc[4] = {z4, z4, z4, z4};

    for (int it = 0; it < npair; ++it) {
        __syncthreads();
        #pragma unroll
        for (int tt = 0; tt < 2; ++tt) {
            int t = (it << 1) + tt;
            if (t < Nt) {
                #pragma unroll
                for (int part = 0; part < 2; ++part) {
                    int lin = part * 256 + tid;
                    int row = lin >> 3, c8 = lin & 7;
                    int off = row * 64 + SWZ(row, c8 * 8);
                    bf16x8 kv = *reinterpret_cast<const bf16x8*>(
                        k + (size_t)(bb * T_SEQ + t * 64 + row) * H_DIM + c8 * 8);
                    *reinterpret_cast<bf16x8*>(&Kt[tt][off]) = kv;
                    bf16x8 vv = *reinterpret_cast<const bf16x8*>(
                        vt + ((size_t)(bb << 6) + row) * T_SEQ + t * 64 + c8 * 8);
                    *reinterpret_cast<bf16x8*>(&Vt[tt][off]) = vv;
                }
            }
        }
        __syncthreads();

        int tm = (it << 1) + par;
        if (tm < Nt) {
            f32x4 sacc[4] = {z4, z4, z4, z4};
            #pragma unroll
            for (int s = 0; s < 2; ++s) {
                int doff = s * 32 + ((lane >> 4) << 3);
                #pragma unroll
                for (int ct = 0; ct < 4; ++ct) {
                    int kr = (ct << 4) + (lane & 15);
                    bf16x8 bfv = *reinterpret_cast<const bf16x8*>(&Kt[par][kr * 64 + SWZ(kr, doff)]);
                    sacc[ct] = __builtin_amdgcn_mfma_f32_16x16x32_bf16(qf[s], bfv, sacc[ct], 0, 0, 0);
                }
            }
            if (tm == Nt - 1) {
                int qgb = q0 + (band << 4) + ((lane >> 4) << 2);
                #pragma unroll
                for (int ct = 0; ct < 4; ++ct) {
                    int kg = tm * 64 + (ct << 4) + (lane & 15);
                    #pragma unroll
                    for (int i = 0; i < 4; ++i)
                        if (kg > qgb + i) sacc[ct][i] = -1e30f;
                }
            }
            #pragma unroll
            for (int i = 0; i < 4; ++i) {
                float s0 = sacc[0][i], s1 = sacc[1][i], s2 = sacc[2][i], s3 = sacc[3][i];
                float tmax = fmaxf(fmaxf(s0, s1), fmaxf(s2, s3));
                tmax = fmaxf(tmax, __shfl_xor(tmax, 1));
                tmax = fmaxf(tmax, __shfl_xor(tmax, 2));
                tmax = fmaxf(tmax, __shfl_xor(tmax, 4));
                tmax = fmaxf(tmax, __shfl_xor(tmax, 8));
                float mnew = fmaxf(mreg[i], tmax);
                float sc = __expf(mreg[i] - mnew);
                mreg[i] = mnew;
                float p0 = __expf(s0 - mnew), p1 = __expf(s1 - mnew);
                float p2 = __expf(s2 - mnew), p3 = __expf(s3 - mnew);
                float ps = p0 + p1 + p2 + p3;
                ps += __shfl_xor(ps, 1); ps += __shfl_xor(ps, 2);
                ps += __shfl_xor(ps, 4); ps += __shfl_xor(ps, 8);
                lreg[i] = lreg[i] * sc + ps;
                oacc[0][i] *= sc; oacc[1][i] *= sc; oacc[2][i] *= sc; oacc[3][i] *= sc;
                int rq = ((lane >> 4) << 2) + i;
                short* pr = &Ps[w][rq * 64];
                pr[SWZ(rq, (0 << 4) + (lane & 15))] = f2bf(p0);
                pr[SWZ(rq, (1 << 4) + (lane & 15))] = f2bf(p1);
                pr[SWZ(rq, (2 << 4) + (lane & 15))] = f2bf(p2);
                pr[SWZ(rq, (3 << 4) + (lane & 15))] = f2bf(p3);
            }
            int qa = lane & 15;
            #pragma unroll
            for (int dt = 0; dt < 4; ++dt) {
                int vr = (dt << 4) + (lane & 15);
                #pragma unroll
                for (int s = 0; s < 2; ++s) {
                    int koff = s * 32 + ((lane >> 4) << 3);
                    bf16x8 af = *reinterpret_cast<const bf16x8*>(&Ps[w][qa * 64 + SWZ(qa, koff)]);
                    bf16x8 bfv = *reinterpret_cast<const bf16x8*>(&Vt[par][vr * 64 + SWZ(vr, koff)]);
                    oacc[dt] = __builtin_amdgcn_mfma_f32_16x16x32_bf16(af, bfv, oacc[dt], 0, 0, 0);
                }
            }
        }
    }

    __syncthreads();
    if (par == 1) {
        int rq0 = (lane >> 4) << 2;
        #pragma unroll
        for (int dt = 0; dt < 4; ++dt)
            #pragma unroll
            for (int i = 0; i < 4; ++i)
                Om[band][rq0 + i][(dt << 4) + (lane & 15)] = oacc[dt][i];
        if ((lane & 15) == 0) {
            #pragma unroll
            for (int i = 0; i < 4; ++i) { Mm[band][rq0 + i] = mreg[i]; Lm[band][rq0 + i] = lreg[i]; }
        }
    }
    __syncthreads();
    if (par == 0) {
        #pragma unroll
        for (int i = 0; i < 4; ++i) {
            int rq = ((lane >> 4) << 2) + i;
            float m1 = Mm[band][rq], l1 = Lm[band][rq];
            float mm = fmaxf(mreg[i], m1);
            float f0 = __expf(mreg[i] - mm), f1 = __expf(m1 - mm);
            float inv = 1.f / (lreg[i] * f0 + l1 * f1);
            size_t orow = (size_t)(bb * T_SEQ + q0 + (band << 4) + rq) * H_DIM;
            #pragma unroll
            for (int dt = 0; dt < 4; ++dt) {
                float o1 = Om[band][rq][(dt << 4) + (lane & 15)];
                out[orow + (dt << 4) + (lane & 15)] = (oacc[dt][i] * f0 + o1 * f1) * inv;
            }
        }
    }
}

extern "C" void kernel_launch(void* const* d_in, const int* in_sizes, int n_in,
                              void* d_out, int out_size, void* d_ws, size_t ws_size,
                              hipStream_t stream) {
    const float* x  = (const float*)d_in[0];
    const float* Wk = (const float*)d_in[1];
    const float* Wq = (const float*)d_in[2];
    const float* Wv = (const float*)d_in[3];
    float* out = (float*)d_out;

    short* ws  = (short*)d_ws;
    short* qb  = ws + Q_OFF;
    short* kb  = ws + K_OFF;
    short* vtb = ws + VT_OFF;
    short* wtb = ws + WT_OFF;
    short* xbp = ws + XB_OFF;

    const size_t need_bytes = ((size_t)XB_OFF + (size_t)BT * E_DIM) * sizeof(short);
    if (ws_size >= need_bytes) {
        wt_prep_frag<<<96, 256, 0, stream>>>(Wk, Wq, Wv, wtb);
        xcvt<<<(BT * E_DIM / 8) / 256, 256, 0, stream>>>(x, xbp);
        proj2<<<BT / 32, 256, 0, stream>>>(xbp, wtb, qb, kb, vtb);
    } else {
        wt_prep_old<<<768, 256, 0, stream>>>(Wk, Wq, Wv, wtb);
        proj_old<<<BT / 32, 256, 0, stream>>>(x, wtb, qb, kb, vtb);
    }
    attn_mfma<<<512, 256, 0, stream>>>(qb, kb, vtb, out);
}

// Round 7
// 67.038 us; speedup vs baseline: 3.7678x; 1.1455x over previous
//
#include <hip/hip_runtime.h>
#include <cstdint>

#define BATCH 8
#define T_SEQ 2048
#define E_DIM 1024
#define H_DIM 64
#define BT (BATCH * T_SEQ)

typedef __attribute__((ext_vector_type(8))) short bf16x8;   // 8 bf16 = 4 VGPR
typedef __attribute__((ext_vector_type(4))) float f32x4;
typedef __attribute__((ext_vector_type(4))) short s16x4;

// fp32 -> bf16 bits, round-to-nearest-even
static __device__ __forceinline__ short f2bf(float f) {
    uint32_t b = __float_as_uint(f);
    b += 0x7fffu + ((b >> 16) & 1u);
    return (short)(b >> 16);
}

// ws element offsets (short units)
#define Q_OFF   0
#define K_OFF   (BT * H_DIM)                // kb frag-linear
#define VT_OFF  (2 * BT * H_DIM)            // vb frag-linear
#define WT_OFF  (3 * BT * H_DIM)
#define XB_OFF  (WT_OFF + 3 * 64 * 1024)    // xb fragment-linear bf16

static __device__ __forceinline__ void glds16(const void* g, void* l) {
    __builtin_amdgcn_global_load_lds(
        (const __attribute__((address_space(1))) void*)g,
        (__attribute__((address_space(3))) void*)l, 16, 0, 0);
}

// Fragment-linear layouts:
//   A-frag lane l: row = l&15, k = (l>>4)*8 + e
//   xb  [rt][kt][lane][8]                      rt = row/16, kt = k/32
//   wt_b[f][kt][lane][8]                       f = m*4+ct, col = ct*16+(l&15)
//   kb  [b][t][ct][s][lane][8] : K[token=t*64+ct*16+(l&15)][d=s*32+(l>>4)*8+e]
//   vb  [b][t][dt][s][lane][8] : V[token=t*64+s*32+(l>>4)*8+e][d=dt*16+(l&15)]

// ---- W -> wt_b (fragment-linear bf16) ----
__global__ void wt_prep_frag(const float* __restrict__ Wk, const float* __restrict__ Wq,
                             const float* __restrict__ Wv, short* __restrict__ wtb) {
    int gid = blockIdx.x * 256 + threadIdx.x;       // 0..24575
    int lane = gid & 63;
    int kt = (gid >> 6) & 31;
    int f = gid >> 11;                               // 0..11
    int m = f >> 2, ct = f & 3;
    int col = (ct << 4) | (lane & 15);
    int k0 = (kt << 5) | (((lane >> 4) & 3) << 3);
    const float* W = (m == 0) ? Wk : ((m == 1) ? Wq : Wv);
    bf16x8 v;
    #pragma unroll
    for (int e = 0; e < 8; ++e) v[e] = f2bf(W[(size_t)(k0 + e) * H_DIM + col]);
    *reinterpret_cast<bf16x8*>(wtb + (size_t)gid * 8) = v;
}

// ---- x fp32 -> xb bf16 fragment-linear (streaming) ----
__global__ __launch_bounds__(256) void xcvt(const float* __restrict__ x, short* __restrict__ xb) {
    int gid = blockIdx.x * 256 + threadIdx.x;
    int lane = gid & 63;
    int kt = (gid >> 6) & 31;
    int rt = gid >> 11;
    int row = (rt << 4) | (lane & 15);
    int k0 = (kt << 5) | (((lane >> 4) & 3) << 3);
    const float* xp = x + (size_t)row * E_DIM + k0;
    float4 a = *reinterpret_cast<const float4*>(xp);
    float4 b = *reinterpret_cast<const float4*>(xp + 4);
    bf16x8 v;
    v[0] = f2bf(a.x); v[1] = f2bf(a.y); v[2] = f2bf(a.z); v[3] = f2bf(a.w);
    v[4] = f2bf(b.x); v[5] = f2bf(b.y); v[6] = f2bf(b.z); v[7] = f2bf(b.w);
    *reinterpret_cast<bf16x8*>(xb + (size_t)gid * 8) = v;
}

// ---- projection: A direct frag loads, B glds-staged, split-K x2 ----
__global__ __launch_bounds__(256, 2) void proj2(
    const short* __restrict__ xb, const short* __restrict__ wtb,
    short* __restrict__ qo, short* __restrict__ kb_, short* __restrict__ vb_)
{
    __shared__ __align__(16) short Bs[2][24 * 512];   // 2 x 24KB

    const int tid  = threadIdx.x;
    const int lane = tid & 63;
    const int w    = tid >> 6;
    const int kh   = w >> 1;             // k-half (512 k each)
    const int rtl  = w & 1;              // row-tile within block
    const int rt_g = blockIdx.x * 2 + rtl;

    const f32x4 z4 = {0.f, 0.f, 0.f, 0.f};
    f32x4 acc[12];
    #pragma unroll
    for (int f = 0; f < 12; ++f) acc[f] = z4;

    const short* abase = xb + ((size_t)rt_g * 32 + kh * 16) * 512 + lane * 8;

    #define STAGE(buf, s)                                                              \
        {                                                                              \
            _Pragma("unroll")                                                          \
            for (int ci = 0; ci < 6; ++ci) {                                           \
                int c = w * 6 + ci;                                                    \
                int f = c % 12, khc = c / 12;                                          \
                const short* src = wtb + (((size_t)f * 32 + khc * 16 + (s)) * 64 + lane) * 8; \
                glds16(src, &Bs[buf][c * 512]);                                        \
            }                                                                          \
        }

    STAGE(0, 0);
    bf16x8 afc = *reinterpret_cast<const bf16x8*>(abase);
    __syncthreads();

    int buf = 0;
    bf16x8 afn;
    for (int s = 0; s < 16; ++s) {
        if (s < 15) {
            STAGE(buf ^ 1, s + 1);
            afn = *reinterpret_cast<const bf16x8*>(abase + (size_t)(s + 1) * 512);
        }
        #pragma unroll
        for (int f = 0; f < 12; ++f) {
            bf16x8 bfv = *reinterpret_cast<const bf16x8*>(&Bs[buf][(kh * 12 + f) * 512 + lane * 8]);
            acc[f] = __builtin_amdgcn_mfma_f32_16x16x32_bf16(afc, bfv, acc[f], 0, 0, 0);
        }
        __syncthreads();
        afc = afn;
        buf ^= 1;
    }

    float* mrg = reinterpret_cast<float*>(&Bs[0][0]);
    if (kh == 1) {
        #pragma unroll
        for (int f = 0; f < 12; ++f)
            *reinterpret_cast<f32x4*>(mrg + ((size_t)(rtl * 12 + f) * 64 + lane) * 4) = acc[f];
    }
    __syncthreads();
    if (kh == 0) {
        const int col16 = lane & 15, rowb = (lane >> 4) << 2;
        const int R0 = rt_g * 16 + rowb;
        #pragma unroll
        for (int m = 0; m < 3; ++m) {
            #pragma unroll
            for (int ct = 0; ct < 4; ++ct) {
                int f = m * 4 + ct;
                f32x4 v = acc[f];
                f32x4 o = *reinterpret_cast<const f32x4*>(mrg + ((size_t)(rtl * 12 + f) * 64 + lane) * 4);
                v.x += o.x; v.y += o.y; v.z += o.z; v.w += o.w;
                int C = (ct << 4) | col16;
                #pragma unroll
                for (int i = 0; i < 4; ++i) {
                    int R = R0 + i;
                    int b = R >> 11, tok = R & 2047, tt = tok >> 6;
                    if (m == 1) {
                        qo[(size_t)R * H_DIM + C] = f2bf(v[i] * 0.125f);   // fold 1/sqrt(64)
                    } else if (m == 0) {
                        int ctk = (tok >> 4) & 3, lnk = (tok & 15) | (((C >> 3) & 3) << 4);
                        int sk = C >> 5, ek = C & 7;
                        kb_[(((((size_t)b * 32 + tt) * 4 + ctk) * 2 + sk) * 64 + lnk) * 8 + ek] = f2bf(v[i]);
                    } else {
                        int sv = (tok >> 5) & 1, gv = (tok >> 3) & 3, ev = tok & 7;
                        int dtv = C >> 4, lnv = (C & 15) | (gv << 4);
                        vb_[(((((size_t)b * 32 + tt) * 4 + dtv) * 2 + sv) * 64 + lnv) * 8 + ev] = f2bf(v[i]);
                    }
                }
            }
        }
    }
}

// ---- attention: barrier-free K-loop, frag-linear K/V direct from L2 ----
#define SWZ(row, off) ((off) ^ (((row) & 7) << 3))

__global__ __launch_bounds__(512, 4) void attn3(
    const short* __restrict__ q, const short* __restrict__ kb,
    const short* __restrict__ vb, float* __restrict__ out)
{
    __shared__ __align__(16) short Ps[8][16 * 64];     // per-wave, barrier-free
    __shared__ float Og[4][16][64];
    __shared__ float Mg[4][16], Lg[4][16];

    const int tid  = threadIdx.x;
    const int lane = tid & 63;
    const int w    = tid >> 6;          // 0..7
    const int band = w & 1;             // q sub-band (16 rows)
    const int kq   = w >> 1;            // 4-way split-K
    const int bb   = blockIdx.x & 7;
    const int p    = 63 - (blockIdx.x >> 3);   // LPT: heavy q-tiles first

    const int q0 = p << 5;
    const int Nt = (p >> 1) + 1;

    const int qrowA = q0 + (band << 4) + (lane & 15);
    bf16x8 qf[2];
    #pragma unroll
    for (int s = 0; s < 2; ++s)
        qf[s] = *reinterpret_cast<const bf16x8*>(
            q + (size_t)(bb * T_SEQ + qrowA) * H_DIM + s * 32 + ((lane >> 4) << 3));

    const f32x4 z4 = {0.f, 0.f, 0.f, 0.f};
    float mreg[4] = {-1e30f, -1e30f, -1e30f, -1e30f};
    float lreg[4] = {0.f, 0.f, 0.f, 0.f};
    f32x4 oacc[4] = {z4, z4, z4, z4};

    const short* kbb = kb + (size_t)bb * 32 * 4096;
    const short* vbb = vb + (size_t)bb * 32 * 4096;

    for (int t = kq; t < Nt; t += 4) {
        const short* kt = kbb + (size_t)t * 4096 + lane * 8;
        // ---- S = Q . K^T ----
        f32x4 sacc[4] = {z4, z4, z4, z4};
        #pragma unroll
        for (int s = 0; s < 2; ++s)
            #pragma unroll
            for (int ct = 0; ct < 4; ++ct) {
                bf16x8 bfv = *reinterpret_cast<const bf16x8*>(kt + (ct * 2 + s) * 512);
                sacc[ct] = __builtin_amdgcn_mfma_f32_16x16x32_bf16(qf[s], bfv, sacc[ct], 0, 0, 0);
            }
        // ---- causal mask (only the diagonal tile) ----
        if (t == Nt - 1) {
            int qgb = q0 + (band << 4) + ((lane >> 4) << 2);
            #pragma unroll
            for (int ct = 0; ct < 4; ++ct) {
                int kg = t * 64 + (ct << 4) + (lane & 15);
                #pragma unroll
                for (int i = 0; i < 4; ++i)
                    if (kg > qgb + i) sacc[ct][i] = -1e30f;
            }
        }
        // ---- online softmax ----
        #pragma unroll
        for (int i = 0; i < 4; ++i) {
            float s0 = sacc[0][i], s1 = sacc[1][i], s2 = sacc[2][i], s3 = sacc[3][i];
            float tmax = fmaxf(fmaxf(s0, s1), fmaxf(s2, s3));
            tmax = fmaxf(tmax, __shfl_xor(tmax, 1));
            tmax = fmaxf(tmax, __shfl_xor(tmax, 2));
            tmax = fmaxf(tmax, __shfl_xor(tmax, 4));
            tmax = fmaxf(tmax, __shfl_xor(tmax, 8));
            float mnew = fmaxf(mreg[i], tmax);
            float sc = __expf(mreg[i] - mnew);
            mreg[i] = mnew;
            float p0 = __expf(s0 - mnew), p1 = __expf(s1 - mnew);
            float p2 = __expf(s2 - mnew), p3 = __expf(s3 - mnew);
            float ps = p0 + p1 + p2 + p3;
            ps += __shfl_xor(ps, 1); ps += __shfl_xor(ps, 2);
            ps += __shfl_xor(ps, 4); ps += __shfl_xor(ps, 8);
            lreg[i] = lreg[i] * sc + ps;
            oacc[0][i] *= sc; oacc[1][i] *= sc; oacc[2][i] *= sc; oacc[3][i] *= sc;
            int rq = ((lane >> 4) << 2) + i;
            short* pr = &Ps[w][rq * 64];
            pr[SWZ(rq, (0 << 4) + (lane & 15))] = f2bf(p0);
            pr[SWZ(rq, (1 << 4) + (lane & 15))] = f2bf(p1);
            pr[SWZ(rq, (2 << 4) + (lane & 15))] = f2bf(p2);
            pr[SWZ(rq, (3 << 4) + (lane & 15))] = f2bf(p3);
        }
        // ---- O += P . V ----
        const short* vt_ = vbb + (size_t)t * 4096 + lane * 8;
        int qa = lane & 15;
        #pragma unroll
        for (int dt = 0; dt < 4; ++dt)
            #pragma unroll
            for (int s = 0; s < 2; ++s) {
                int koff = s * 32 + ((lane >> 4) << 3);
                bf16x8 af  = *reinterpret_cast<const bf16x8*>(&Ps[w][qa * 64 + SWZ(qa, koff)]);
                bf16x8 bfv = *reinterpret_cast<const bf16x8*>(vt_ + (dt * 2 + s) * 512);
                oacc[dt] = __builtin_amdgcn_mfma_f32_16x16x32_bf16(af, bfv, oacc[dt], 0, 0, 0);
            }
    }

    // ---- merge the 4 split-K states per band ----
    __syncthreads();
    if (kq >= 2) {
        int slot = (band << 1) | (kq - 2);
        #pragma unroll
        for (int i = 0; i < 4; ++i) {
            int rq = ((lane >> 4) << 2) + i;
            #pragma unroll
            for (int dt = 0; dt < 4; ++dt)
                Og[slot][rq][(dt << 4) + (lane & 15)] = oacc[dt][i];
            if ((lane & 15) == 0) { Mg[slot][rq] = mreg[i]; Lg[slot][rq] = lreg[i]; }
        }
    }
    __syncthreads();
    if (kq < 2) {
        int slot = (band << 1) | kq;
        #pragma unroll
        for (int i = 0; i < 4; ++i) {
            int rq = ((lane >> 4) << 2) + i;
            float m1 = Mg[slot][rq], l1 = Lg[slot][rq];
            float mm = fmaxf(mreg[i], m1);
            float f0 = __expf(mreg[i] - mm), f1 = __expf(m1 - mm);
            mreg[i] = mm;
            lreg[i] = lreg[i] * f0 + l1 * f1;
            #pragma unroll
            for (int dt = 0; dt < 4; ++dt)
                oacc[dt][i] = oacc[dt][i] * f0 + Og[slot][rq][(dt << 4) + (lane & 15)] * f1;
        }
    }
    __syncthreads();
    if (kq == 1) {
        int slot = (band << 1) | 1;
        #pragma unroll
        for (int i = 0; i < 4; ++i) {
            int rq = ((lane >> 4) << 2) + i;
            #pragma unroll
            for (int dt = 0; dt < 4; ++dt)
                Og[slot][rq][(dt << 4) + (lane & 15)] = oacc[dt][i];
            if ((lane & 15) == 0) { Mg[slot][rq] = mreg[i]; Lg[slot][rq] = lreg[i]; }
        }
    }
    __syncthreads();
    if (kq == 0) {
        int slot = (band << 1) | 1;
        #pragma unroll
        for (int i = 0; i < 4; ++i) {
            int rq = ((lane >> 4) << 2) + i;
            float m1 = Mg[slot][rq], l1 = Lg[slot][rq];
            float mm = fmaxf(mreg[i], m1);
            float f0 = __expf(mreg[i] - mm), f1 = __expf(m1 - mm);
            float l  = lreg[i] * f0 + l1 * f1;
            float inv = 1.f / l;
            size_t orow = (size_t)(bb * T_SEQ + q0 + (band << 4) + rq) * H_DIM;
            #pragma unroll
            for (int dt = 0; dt < 4; ++dt) {
                float ov = oacc[dt][i] * f0 + Og[slot][rq][(dt << 4) + (lane & 15)] * f1;
                out[orow + (dt << 4) + (lane & 15)] = ov * inv;
            }
        }
    }
}

extern "C" void kernel_launch(void* const* d_in, const int* in_sizes, int n_in,
                              void* d_out, int out_size, void* d_ws, size_t ws_size,
                              hipStream_t stream) {
    const float* x  = (const float*)d_in[0];
    const float* Wk = (const float*)d_in[1];
    const float* Wq = (const float*)d_in[2];
    const float* Wv = (const float*)d_in[3];
    float* out = (float*)d_out;

    short* ws  = (short*)d_ws;
    short* qb  = ws + Q_OFF;
    short* kbp = ws + K_OFF;
    short* vbp = ws + VT_OFF;
    short* wtb = ws + WT_OFF;
    short* xbp = ws + XB_OFF;

    wt_prep_frag<<<96, 256, 0, stream>>>(Wk, Wq, Wv, wtb);
    xcvt<<<(BT * E_DIM / 8) / 256, 256, 0, stream>>>(x, xbp);
    proj2<<<BT / 32, 256, 0, stream>>>(xbp, wtb, qb, kbp, vbp);
    attn3<<<512, 512, 0, stream>>>(qb, kbp, vbp, out);
}

// Round 8
// 53.629 us; speedup vs baseline: 4.7099x; 1.2500x over previous
//
#include <hip/hip_runtime.h>
#include <cstdint>

#define BATCH 8
#define T_SEQ 2048
#define E_DIM 1024
#define H_DIM 64
#define BT (BATCH * T_SEQ)

typedef __attribute__((ext_vector_type(8))) short bf16x8;   // 8 bf16 = 4 VGPR
typedef __attribute__((ext_vector_type(4))) float f32x4;

// fp32 -> bf16 bits, round-to-nearest-even
static __device__ __forceinline__ short f2bf(float f) {
    uint32_t b = __float_as_uint(f);
    b += 0x7fffu + ((b >> 16) & 1u);
    return (short)(b >> 16);
}

// ws element offsets (short units)
#define Q_OFF   0
#define K_OFF   (BT * H_DIM)                // kb frag-linear
#define VT_OFF  (2 * BT * H_DIM)            // vb frag-linear
#define WT_OFF  (3 * BT * H_DIM)            // wt_b frag-linear (384 KB)

static __device__ __forceinline__ void glds16(const void* g, void* l) {
    __builtin_amdgcn_global_load_lds(
        (const __attribute__((address_space(1))) void*)g,
        (__attribute__((address_space(3))) void*)l, 16, 0, 0);
}

// Fragment-linear layouts:
//   A-frag lane l: row = l&15, k = (l>>4)*8 + e
//   wt_b[f][kt][lane][8]       f = m*4+ct, col = ct*16+(l&15), kt = k/32
//   kb  [b][t][ct][s][lane][8] : K[token=t*64+ct*16+(l&15)][d=s*32+(l>>4)*8+e]
//   vb  [b][t][dt][s][lane][8] : V[token=t*64+s*32+(l>>4)*8+e][d=dt*16+(l&15)]

// ---- W -> wt_b (fragment-linear bf16) ----
__global__ void wt_prep_frag(const float* __restrict__ Wk, const float* __restrict__ Wq,
                             const float* __restrict__ Wv, short* __restrict__ wtb) {
    int gid = blockIdx.x * 256 + threadIdx.x;       // 0..24575
    int lane = gid & 63;
    int kt = (gid >> 6) & 31;
    int f = gid >> 11;                               // 0..11
    int m = f >> 2, ct = f & 3;
    int col = (ct << 4) | (lane & 15);
    int k0 = (kt << 5) | (((lane >> 4) & 3) << 3);
    const float* W = (m == 0) ? Wk : ((m == 1) ? Wq : Wv);
    bf16x8 v;
    #pragma unroll
    for (int e = 0; e < 8; ++e) v[e] = f2bf(W[(size_t)(k0 + e) * H_DIM + col]);
    *reinterpret_cast<bf16x8*>(wtb + (size_t)gid * 8) = v;
}

// ---- fused projection: x fp32 streamed through LDS (bf16 frag order), B glds-staged ----
__global__ __launch_bounds__(256, 2) void proj_fused(
    const float* __restrict__ x, const short* __restrict__ wtb,
    short* __restrict__ qo, short* __restrict__ kb_, short* __restrict__ vb_)
{
    __shared__ __align__(16) short Bs[2][24 * 512];   // 2 x 24KB  (B tiles)
    __shared__ __align__(16) short Xs[2][4 * 64 * 8]; // 2 x 4KB   (A tiles, frag order)

    const int tid  = threadIdx.x;
    const int lane = tid & 63;
    const int w    = tid >> 6;
    const int kh   = w >> 1;             // k-half (512 k each)
    const int rtl  = w & 1;              // row-tile within block
    const int rt_g = blockIdx.x * 2 + rtl;
    const int row0 = blockIdx.x * 32;

    const f32x4 z4 = {0.f, 0.f, 0.f, 0.f};
    f32x4 acc[12];
    #pragma unroll
    for (int f = 0; f < 12; ++f) acc[f] = z4;

    // B staging: wave w pulls 6 of 24 1KB chunks (c = khc*12+f)
    #define STAGE_B(buf, s)                                                            \
        {                                                                              \
            _Pragma("unroll")                                                          \
            for (int ci = 0; ci < 6; ++ci) {                                           \
                int c = w * 6 + ci;                                                    \
                int f = c % 12, khc = c / 12;                                          \
                const short* src = wtb + (((size_t)f * 32 + khc * 16 + (s)) * 64 + lane) * 8; \
                glds16(src, &Bs[buf][c * 512]);                                        \
            }                                                                          \
        }

    // A staging: thread -> row = tid>>3 (0..31), k8 = tid&7 (two 32-k strips)
    #define STAGE_A(buf, s)                                                            \
        {                                                                              \
            int row = tid >> 3, k8 = tid & 7;                                          \
            int khs = k8 >> 2, j = k8 & 3;                                             \
            const float* xp = x + (size_t)(row0 + row) * E_DIM + khs * 512 + (s) * 32 + j * 8; \
            float4 a = *reinterpret_cast<const float4*>(xp);                           \
            float4 b = *reinterpret_cast<const float4*>(xp + 4);                       \
            bf16x8 v;                                                                  \
            v[0] = f2bf(a.x); v[1] = f2bf(a.y); v[2] = f2bf(a.z); v[3] = f2bf(a.w);    \
            v[4] = f2bf(b.x); v[5] = f2bf(b.y); v[6] = f2bf(b.z); v[7] = f2bf(b.w);    \
            int c = ((row >> 4) << 1) | khs;                                           \
            int slot = (j << 4) | (row & 15);                                          \
            *reinterpret_cast<bf16x8*>(&Xs[buf][(c * 64 + slot) * 8]) = v;             \
        }

    STAGE_B(0, 0);
    STAGE_A(0, 0);
    __syncthreads();

    const int ac = ((rtl << 1) | kh) * 64;   // this wave's A chunk base (slots)
    int buf = 0;
    for (int s = 0; s < 16; ++s) {
        if (s < 15) {
            STAGE_B(buf ^ 1, s + 1);
            STAGE_A(buf ^ 1, s + 1);
        }
        bf16x8 afc = *reinterpret_cast<const bf16x8*>(&Xs[buf][(ac + lane) * 8]);
        #pragma unroll
        for (int f = 0; f < 12; ++f) {
            bf16x8 bfv = *reinterpret_cast<const bf16x8*>(&Bs[buf][(kh * 12 + f) * 512 + lane * 8]);
            acc[f] = __builtin_amdgcn_mfma_f32_16x16x32_bf16(afc, bfv, acc[f], 0, 0, 0);
        }
        __syncthreads();
        buf ^= 1;
    }

    // merge k-halves (mrg aliases Bs[0]; last MFMA reads were Bs[1])
    float* mrg = reinterpret_cast<float*>(&Bs[0][0]);
    if (kh == 1) {
        #pragma unroll
        for (int f = 0; f < 12; ++f)
            *reinterpret_cast<f32x4*>(mrg + ((size_t)(rtl * 12 + f) * 64 + lane) * 4) = acc[f];
    }
    __syncthreads();
    if (kh == 0) {
        const int col16 = lane & 15, rowb = (lane >> 4) << 2;
        const int R0 = rt_g * 16 + rowb;
        #pragma unroll
        for (int m = 0; m < 3; ++m) {
            #pragma unroll
            for (int ct = 0; ct < 4; ++ct) {
                int f = m * 4 + ct;
                f32x4 v = acc[f];
                f32x4 o = *reinterpret_cast<const f32x4*>(mrg + ((size_t)(rtl * 12 + f) * 64 + lane) * 4);
                v.x += o.x; v.y += o.y; v.z += o.z; v.w += o.w;
                int C = (ct << 4) | col16;
                #pragma unroll
                for (int i = 0; i < 4; ++i) {
                    int R = R0 + i;
                    int b = R >> 11, tok = R & 2047, tt = tok >> 6;
                    if (m == 1) {
                        qo[(size_t)R * H_DIM + C] = f2bf(v[i] * 0.125f);   // fold 1/sqrt(64)
                    } else if (m == 0) {
                        int ctk = (tok >> 4) & 3, lnk = (tok & 15) | (((C >> 3) & 3) << 4);
                        int sk = C >> 5, ek = C & 7;
                        kb_[(((((size_t)b * 32 + tt) * 4 + ctk) * 2 + sk) * 64 + lnk) * 8 + ek] = f2bf(v[i]);
                    } else {
                        int sv = (tok >> 5) & 1, gv = (tok >> 3) & 3, ev = tok & 7;
                        int dtv = C >> 4, lnv = (C & 15) | (gv << 4);
                        vb_[(((((size_t)b * 32 + tt) * 4 + dtv) * 2 + sv) * 64 + lnv) * 8 + ev] = f2bf(v[i]);
                    }
                }
            }
        }
    }
}

// ---- attention: barrier-free K-loop, frag-linear K/V direct from L2 ----
#define SWZ(row, off) ((off) ^ (((row) & 7) << 3))

__global__ __launch_bounds__(512, 4) void attn3(
    const short* __restrict__ q, const short* __restrict__ kb,
    const short* __restrict__ vb, float* __restrict__ out)
{
    __shared__ __align__(16) short Ps[8][16 * 64];     // per-wave, barrier-free
    __shared__ float Og[4][16][64];
    __shared__ float Mg[4][16], Lg[4][16];

    const int tid  = threadIdx.x;
    const int lane = tid & 63;
    const int w    = tid >> 6;          // 0..7
    const int band = w & 1;             // q sub-band (16 rows)
    const int kq   = w >> 1;            // 4-way split-K
    const int bb   = blockIdx.x & 7;
    const int j    = blockIdx.x >> 3;
    const int p    = (j < 32) ? (63 - j) : (j - 32);   // heavy+light pairing per CU

    const int q0 = p << 5;
    const int Nt = (p >> 1) + 1;

    const int qrowA = q0 + (band << 4) + (lane & 15);
    bf16x8 qf[2];
    #pragma unroll
    for (int s = 0; s < 2; ++s)
        qf[s] = *reinterpret_cast<const bf16x8*>(
            q + (size_t)(bb * T_SEQ + qrowA) * H_DIM + s * 32 + ((lane >> 4) << 3));

    const f32x4 z4 = {0.f, 0.f, 0.f, 0.f};
    float mreg[4] = {-1e30f, -1e30f, -1e30f, -1e30f};
    float lreg[4] = {0.f, 0.f, 0.f, 0.f};
    f32x4 oacc[4] = {z4, z4, z4, z4};

    const short* kbb = kb + (size_t)bb * 32 * 4096;
    const short* vbb = vb + (size_t)bb * 32 * 4096;

    for (int t = kq; t < Nt; t += 4) {
        const short* kt = kbb + (size_t)t * 4096 + lane * 8;
        // ---- S = Q . K^T ----
        f32x4 sacc[4] = {z4, z4, z4, z4};
        #pragma unroll
        for (int s = 0; s < 2; ++s)
            #pragma unroll
            for (int ct = 0; ct < 4; ++ct) {
                bf16x8 bfv = *reinterpret_cast<const bf16x8*>(kt + (ct * 2 + s) * 512);
                sacc[ct] = __builtin_amdgcn_mfma_f32_16x16x32_bf16(qf[s], bfv, sacc[ct], 0, 0, 0);
            }
        // ---- V preload (L2 latency hides under softmax) ----
        const short* vt_ = vbb + (size_t)t * 4096 + lane * 8;
        bf16x8 Vc[8];
        #pragma unroll
        for (int u = 0; u < 8; ++u)
            Vc[u] = *reinterpret_cast<const bf16x8*>(vt_ + u * 512);
        // ---- causal mask (only the diagonal tile) ----
        if (t == Nt - 1) {
            int qgb = q0 + (band << 4) + ((lane >> 4) << 2);
            #pragma unroll
            for (int ct = 0; ct < 4; ++ct) {
                int kg = t * 64 + (ct << 4) + (lane & 15);
                #pragma unroll
                for (int i = 0; i < 4; ++i)
                    if (kg > qgb + i) sacc[ct][i] = -1e30f;
            }
        }
        // ---- online softmax ----
        #pragma unroll
        for (int i = 0; i < 4; ++i) {
            float s0 = sacc[0][i], s1 = sacc[1][i], s2 = sacc[2][i], s3 = sacc[3][i];
            float tmax = fmaxf(fmaxf(s0, s1), fmaxf(s2, s3));
            tmax = fmaxf(tmax, __shfl_xor(tmax, 1));
            tmax = fmaxf(tmax, __shfl_xor(tmax, 2));
            tmax = fmaxf(tmax, __shfl_xor(tmax, 4));
            tmax = fmaxf(tmax, __shfl_xor(tmax, 8));
            float mnew = fmaxf(mreg[i], tmax);
            float sc = __expf(mreg[i] - mnew);
            mreg[i] = mnew;
            float p0 = __expf(s0 - mnew), p1 = __expf(s1 - mnew);
            float p2 = __expf(s2 - mnew), p3 = __expf(s3 - mnew);
            float ps = p0 + p1 + p2 + p3;
            ps += __shfl_xor(ps, 1); ps += __shfl_xor(ps, 2);
            ps += __shfl_xor(ps, 4); ps += __shfl_xor(ps, 8);
            lreg[i] = lreg[i] * sc + ps;
            oacc[0][i] *= sc; oacc[1][i] *= sc; oacc[2][i] *= sc; oacc[3][i] *= sc;
            int rq = ((lane >> 4) << 2) + i;
            short* pr = &Ps[w][rq * 64];
            pr[SWZ(rq, (0 << 4) + (lane & 15))] = f2bf(p0);
            pr[SWZ(rq, (1 << 4) + (lane & 15))] = f2bf(p1);
            pr[SWZ(rq, (2 << 4) + (lane & 15))] = f2bf(p2);
            pr[SWZ(rq, (3 << 4) + (lane & 15))] = f2bf(p3);
        }
        // ---- O += P . V ----
        int qa = lane & 15;
        #pragma unroll
        for (int dt = 0; dt < 4; ++dt)
            #pragma unroll
            for (int s = 0; s < 2; ++s) {
                int koff = s * 32 + ((lane >> 4) << 3);
                bf16x8 af = *reinterpret_cast<const bf16x8*>(&Ps[w][qa * 64 + SWZ(qa, koff)]);
                oacc[dt] = __builtin_amdgcn_mfma_f32_16x16x32_bf16(af, Vc[dt * 2 + s], oacc[dt], 0, 0, 0);
            }
    }

    // ---- merge the 4 split-K states per band ----
    __syncthreads();
    if (kq >= 2) {
        int slot = (band << 1) | (kq - 2);
        #pragma unroll
        for (int i = 0; i < 4; ++i) {
            int rq = ((lane >> 4) << 2) + i;
            #pragma unroll
            for (int dt = 0; dt < 4; ++dt)
                Og[slot][rq][(dt << 4) + (lane & 15)] = oacc[dt][i];
            if ((lane & 15) == 0) { Mg[slot][rq] = mreg[i]; Lg[slot][rq] = lreg[i]; }
        }
    }
    __syncthreads();
    if (kq < 2) {
        int slot = (band << 1) | kq;
        #pragma unroll
        for (int i = 0; i < 4; ++i) {
            int rq = ((lane >> 4) << 2) + i;
            float m1 = Mg[slot][rq], l1 = Lg[slot][rq];
            float mm = fmaxf(mreg[i], m1);
            float f0 = __expf(mreg[i] - mm), f1 = __expf(m1 - mm);
            mreg[i] = mm;
            lreg[i] = lreg[i] * f0 + l1 * f1;
            #pragma unroll
            for (int dt = 0; dt < 4; ++dt)
                oacc[dt][i] = oacc[dt][i] * f0 + Og[slot][rq][(dt << 4) + (lane & 15)] * f1;
        }
    }
    __syncthreads();
    if (kq == 1) {
        int slot = (band << 1) | 1;
        #pragma unroll
        for (int i = 0; i < 4; ++i) {
            int rq = ((lane >> 4) << 2) + i;
            #pragma unroll
            for (int dt = 0; dt < 4; ++dt)
                Og[slot][rq][(dt << 4) + (lane & 15)] = oacc[dt][i];
            if ((lane & 15) == 0) { Mg[slot][rq] = mreg[i]; Lg[slot][rq] = lreg[i]; }
        }
    }
    __syncthreads();
    if (kq == 0) {
        int slot = (band << 1) | 1;
        #pragma unroll
        for (int i = 0; i < 4; ++i) {
            int rq = ((lane >> 4) << 2) + i;
            float m1 = Mg[slot][rq], l1 = Lg[slot][rq];
            float mm = fmaxf(mreg[i], m1);
            float f0 = __expf(mreg[i] - mm), f1 = __expf(m1 - mm);
            float l  = lreg[i] * f0 + l1 * f1;
            float inv = 1.f / l;
            size_t orow = (size_t)(bb * T_SEQ + q0 + (band << 4) + rq) * H_DIM;
            #pragma unroll
            for (int dt = 0; dt < 4; ++dt) {
                float ov = oacc[dt][i] * f0 + Og[slot][rq][(dt << 4) + (lane & 15)] * f1;
                out[orow + (dt << 4) + (lane & 15)] = ov * inv;
            }
        }
    }
}

extern "C" void kernel_launch(void* const* d_in, const int* in_sizes, int n_in,
                              void* d_out, int out_size, void* d_ws, size_t ws_size,
                              hipStream_t stream) {
    const float* x  = (const float*)d_in[0];
    const float* Wk = (const float*)d_in[1];
    const float* Wq = (const float*)d_in[2];
    const float* Wv = (const float*)d_in[3];
    float* out = (float*)d_out;

    short* ws  = (short*)d_ws;
    short* qb  = ws + Q_OFF;
    short* kbp = ws + K_OFF;
    short* vbp = ws + VT_OFF;
    short* wtb = ws + WT_OFF;

    wt_prep_frag<<<96, 256, 0, stream>>>(Wk, Wq, Wv, wtb);
    proj_fused<<<BT / 32, 256, 0, stream>>>(x, wtb, qb, kbp, vbp);
    attn3<<<512, 512, 0, stream>>>(qb, kbp, vbp, out);
}